// Round 15
// baseline (615.337 us; speedup 1.0000x reference)
//
#include <hip/hip_runtime.h>
#include <hip/hip_bf16.h>

typedef __attribute__((ext_vector_type(8))) short bf16x8;
typedef __attribute__((ext_vector_type(4))) float f32x4;

static constexpr int NB   = 8;
static constexpr int NN   = 1024;
static constexpr int NE   = 32768;
static constexpr int FIN  = 128;
static constexpr int FH   = 256;
static constexpr int FOUT = 128;
static constexpr int MR   = NB * NN;

__device__ __forceinline__ short f2bf(float f) {
  union { __hip_bfloat16 h; short s; } u;
  u.h = __float2bfloat16(f);
  return u.s;
}

typedef const __attribute__((address_space(1))) void gas_void;
typedef __attribute__((address_space(3))) void las_void;
__device__ __forceinline__ void glds16(short* lds, const short* g) {
  __builtin_amdgcn_global_load_lds((gas_void*)g, (las_void*)lds, 16, 0, 0);
}
__device__ __forceinline__ void BAR() {
  asm volatile("" ::: "memory");
  __builtin_amdgcn_s_barrier();
  asm volatile("" ::: "memory");
}

// ---- graph preprocessing -------------------------------------------------
__global__ void k_deg(const int* __restrict__ dst, int* __restrict__ deg) {
  int e = blockIdx.x * blockDim.x + threadIdx.x;
  if (e < NE) atomicAdd(&deg[dst[e]], 1);
}
// dis computed inline from deg (k_dis merged away)
__global__ void k_adj(const int* __restrict__ src, const int* __restrict__ dst,
                      const int* __restrict__ deg, float* __restrict__ Adj) {
  int t = blockIdx.x * blockDim.x + threadIdx.x;
  if (t < NE) {
    int s = src[t], d = dst[t];
    float ds = rsqrtf((float)(deg[s] + 1));
    float dd = rsqrtf((float)(deg[d] + 1));
    atomicAdd(&Adj[d * NN + s], ds * dd);
  } else if (t < NE + NN) {
    int n = t - NE;
    float dn = rsqrtf((float)(deg[n] + 1));
    atomicAdd(&Adj[n * NN + n], dn * dn);
  }
}

// ---- layout / cast kernels ----------------------------------------------
__global__ __launch_bounds__(256) void k_cast(const float4* __restrict__ S,
                                              short* __restrict__ D) {
  size_t q = (size_t)blockIdx.x * 256 + threadIdx.x;
  float4 a = S[q];
  short4 p;
  p.x = f2bf(a.x); p.y = f2bf(a.y); p.z = f2bf(a.z); p.w = f2bf(a.w);
  *(short4*)&D[q * 4] = p;
}
__global__ __launch_bounds__(256) void k_wt(const float* __restrict__ W1,
                                            const float* __restrict__ Wm,
                                            const float* __restrict__ W2,
                                            short* __restrict__ W1T,
                                            short* __restrict__ WmT,
                                            short* __restrict__ W2T) {
  int idx = blockIdx.x * 256 + threadIdx.x;
  if (idx < 128 * 256) {
    int r = idx >> 8, c = idx & 255;
    W1T[c * 128 + r] = f2bf(W1[idx]);
  } else if (idx < 128 * 256 + 512 * 256) {
    int k = idx - 128 * 256;
    int r = k >> 8, c = k & 255;
    int h = r >> 8, kk = r & 255;
    WmT[h * 65536 + c * 256 + kk] = f2bf(Wm[k]);
  } else {
    int k = idx - 128 * 256 - 512 * 256;
    int r = k >> 7, c = k & 127;
    W2T[c * 256 + r] = f2bf(W2[k]);
  }
}
// z=0: m_in -> mi_bf (vectorized) + miT (tile transpose); z=1: m_out -> mo_bf
__global__ __launch_bounds__(256) void k_prep(const float* __restrict__ mi,
                                              const float* __restrict__ mo,
                                              short* __restrict__ mi_bf,
                                              short* __restrict__ mo_bf,
                                              short* __restrict__ miT) {
  int tid = threadIdx.x;
  int e0 = blockIdx.x * 64, n0 = blockIdx.y * 64;
  if (blockIdx.z == 1) {
    #pragma unroll
    for (int it = 0; it < 4; ++it) {
      int r = it * 16 + (tid >> 4);
      int c4 = (tid & 15) * 4;
      float4 v = *(const float4*)&mo[(size_t)(e0 + r) * 1024 + n0 + c4];
      short4 p;
      p.x = f2bf(v.x); p.y = f2bf(v.y); p.z = f2bf(v.z); p.w = f2bf(v.w);
      *(short4*)&mo_bf[(size_t)(e0 + r) * 1024 + n0 + c4] = p;
    }
    return;
  }
  __shared__ short tile[64][71];   // odd-ish stride: 4-col scatter hits 16 banks
  #pragma unroll
  for (int it = 0; it < 4; ++it) {
    int r = it * 16 + (tid >> 4);
    int c4 = (tid & 15) * 4;
    float4 v = *(const float4*)&mi[(size_t)(e0 + r) * 1024 + n0 + c4];
    short4 p;
    p.x = f2bf(v.x); p.y = f2bf(v.y); p.z = f2bf(v.z); p.w = f2bf(v.w);
    *(short4*)&mi_bf[(size_t)(e0 + r) * 1024 + n0 + c4] = p;
    tile[c4 + 0][r] = p.x;
    tile[c4 + 1][r] = p.y;
    tile[c4 + 2][r] = p.z;
    tile[c4 + 3][r] = p.w;
  }
  __syncthreads();
  int n = tid >> 2, ec = (tid & 3) * 16;
  #pragma unroll
  for (int q = 0; q < 4; ++q) {
    short4 v;
    v.x = tile[n][ec + q * 4 + 0];
    v.y = tile[n][ec + q * 4 + 1];
    v.z = tile[n][ec + q * 4 + 2];
    v.w = tile[n][ec + q * 4 + 3];
    *(short4*)&miT[(size_t)(n0 + n) * 32768 + e0 + ec + q * 4] = v;
  }
}
// XW2T[f128][(b,node)] = bf16(H2X[node][b*128+f128] / 1024)  (tiled transpose)
__global__ __launch_bounds__(256) void k_repack2(const float* __restrict__ H2X,
                                                 short* __restrict__ XW2T) {
  __shared__ float t[32][33];
  int n0 = blockIdx.x * 32, c0 = blockIdx.y * 32;
  int r = threadIdx.x >> 5, cc = threadIdx.x & 31;
  #pragma unroll
  for (int p = 0; p < 4; ++p)
    t[r + p * 8][cc] = H2X[(size_t)(n0 + r + p * 8) * 1024 + c0 + cc];
  __syncthreads();
  const float inv = 1.0f / 1024.0f;
  #pragma unroll
  for (int p = 0; p < 4; ++p) {
    int c = c0 + r + p * 8;
    int b = c >> 7, f = c & 127;
    XW2T[(size_t)f * 8192 + b * 1024 + n0 + cc] = f2bf(t[cc][r + p * 8] * inv);
  }
}

// ---- proven 128x128 bf16 MFMA GEMM: C = A[M,K] @ BT[N,K]^T ---------------
template <int EPI, int ASRC, int BSEL, bool BIAS, bool RELU>
__launch_bounds__(256)
__global__ void gemm_mfma(const short* __restrict__ Ab, const float* __restrict__ Af,
                          const short* __restrict__ BT, const float* __restrict__ bias,
                          void* __restrict__ Cv,
                          int lda, int ldb, int ldc, int K, int kSplit, int nz2,
                          int zcolB, size_t szA, size_t szB, size_t szC, size_t szC2,
                          float scale) {
  __shared__ __align__(16) short As[128 * 64];
  __shared__ __align__(16) short Bs[128 * 64];

  const int tid = threadIdx.x;
  const int lane = tid & 63, wid = tid >> 6;
  const int wr = wid >> 1, wc = wid & 1;
  const int fr = lane & 15, fq = lane >> 4;
  const int m0 = blockIdx.y * 128, n0 = blockIdx.x * 128;

  int zA = 0, zB = 0, k0 = 0, k1 = K;
  if constexpr (EPI == 1) {
    k0 = blockIdx.z * kSplit; k1 = k0 + kSplit;
  } else {
    zA = (int)blockIdx.z % nz2; zB = (int)blockIdx.z / nz2;
  }
  if constexpr (ASRC == 0) Ab += (size_t)zA * szA;
  else                     Af += (size_t)zA * szA;
  BT += (size_t)zB * szB;
  const int colB = zB * zcolB;

  const int rq = lane >> 3;
  const int ks = (lane & 7) ^ rq;

  f32x4 acc[4][4] = {};

  for (int kt = k0; kt < k1; kt += 64) {
    if constexpr (ASRC == 2) {
      #pragma unroll
      for (int p = 0; p < 4; ++p) {
        int i = p * 256 + tid, row = i >> 3, g = i & 7;
        const float* ap = Af + (size_t)(m0 + row) * lda + kt + g * 8;
        bf16x8 v;
        #pragma unroll
        for (int e = 0; e < 8; ++e) v[e] = f2bf(ap[e]);
        *(bf16x8*)&As[row * 64 + ((g ^ (row & 7)) * 8)] = v;
      }
    } else {
      #pragma unroll
      for (int c = 0; c < 4; ++c) {
        int row = wid * 32 + c * 8 + rq;
        glds16(&As[(wid * 256 + c * 64) * 8],
               Ab + (size_t)(m0 + row) * lda + kt + ks * 8);
      }
    }
    {
      const short* Bsrc;
      int ldbe;
      if constexpr (BSEL == 1) { Bsrc = BT + colB; ldbe = 8192; }
      else                     { Bsrc = BT;        ldbe = ldb;  }
      #pragma unroll
      for (int c = 0; c < 4; ++c) {
        int row = wid * 32 + c * 8 + rq;
        glds16(&Bs[(wid * 256 + c * 64) * 8],
               Bsrc + (size_t)(n0 + row) * ldbe + kt + ks * 8);
      }
    }
    __syncthreads();
    bf16x8 afv[4][2], bfv[4][2];
    #pragma unroll
    for (int i = 0; i < 4; ++i) {
      int row = wr * 64 + i * 16 + fr;
      #pragma unroll
      for (int kh = 0; kh < 2; ++kh)
        afv[i][kh] = *(const bf16x8*)&As[row * 64 + (((kh * 4 + fq) ^ (fr & 7)) * 8)];
    }
    #pragma unroll
    for (int j = 0; j < 4; ++j) {
      int row = wc * 64 + j * 16 + fr;
      #pragma unroll
      for (int kh = 0; kh < 2; ++kh)
        bfv[j][kh] = *(const bf16x8*)&Bs[row * 64 + (((kh * 4 + fq) ^ (fr & 7)) * 8)];
    }
    #pragma unroll
    for (int i = 0; i < 4; ++i)
      #pragma unroll
      for (int j = 0; j < 4; ++j) {
        acc[i][j] = __builtin_amdgcn_mfma_f32_16x16x32_bf16(afv[i][0], bfv[j][0], acc[i][j], 0, 0, 0);
        acc[i][j] = __builtin_amdgcn_mfma_f32_16x16x32_bf16(afv[i][1], bfv[j][1], acc[i][j], 0, 0, 0);
      }
    __syncthreads();
  }

  const size_t cOff = (size_t)zB * szC + (size_t)zA * szC2;
  #pragma unroll
  for (int i = 0; i < 4; ++i) {
    int rowb = m0 + wr * 64 + i * 16 + fq * 4;
    #pragma unroll
    for (int j = 0; j < 4; ++j) {
      int col = n0 + wc * 64 + j * 16 + fr;
      float bv = 0.0f;
      if constexpr (BIAS) bv = bias[col];
      float v0 = acc[i][j][0] + bv, v1 = acc[i][j][1] + bv;
      float v2 = acc[i][j][2] + bv, v3 = acc[i][j][3] + bv;
      if constexpr (RELU) {
        v0 = fmaxf(v0, 0.0f); v1 = fmaxf(v1, 0.0f);
        v2 = fmaxf(v2, 0.0f); v3 = fmaxf(v3, 0.0f);
      }
      if constexpr (EPI == 0) {
        short* Ct = (short*)Cv + cOff;
        short4 pk;
        pk.x = f2bf(v0); pk.y = f2bf(v1); pk.z = f2bf(v2); pk.w = f2bf(v3);
        *(short4*)(Ct + (size_t)col * ldc + rowb) = pk;
      } else if constexpr (EPI == 1) {
        float* Cf = (float*)Cv;
        atomicAdd(&Cf[(size_t)(rowb + 0) * ldc + col], acc[i][j][0] * scale);
        atomicAdd(&Cf[(size_t)(rowb + 1) * ldc + col], acc[i][j][1] * scale);
        atomicAdd(&Cf[(size_t)(rowb + 2) * ldc + col], acc[i][j][2] * scale);
        atomicAdd(&Cf[(size_t)(rowb + 3) * ldc + col], acc[i][j][3] * scale);
      } else if constexpr (EPI == 2) {
        short* Cn = (short*)Cv + cOff;
        Cn[(size_t)(rowb + 0) * ldc + col] = f2bf(v0);
        Cn[(size_t)(rowb + 1) * ldc + col] = f2bf(v1);
        Cn[(size_t)(rowb + 2) * ldc + col] = f2bf(v2);
        Cn[(size_t)(rowb + 3) * ldc + col] = f2bf(v3);
      } else {
        float* Cf = (float*)Cv + cOff;
        Cf[(size_t)(rowb + 0) * ldc + col] = v0;
        Cf[(size_t)(rowb + 1) * ldc + col] = v1;
        Cf[(size_t)(rowb + 2) * ldc + col] = v2;
        Cf[(size_t)(rowb + 3) * ldc + col] = v3;
      }
    }
  }
}

// ---- 8-phase 256x256 edge GEMM + FUSED D epilogue ------------------------
__launch_bounds__(512, 2)
__global__ void egemm8(const short* __restrict__ Ain, const short* __restrict__ Aout,
                       const short* __restrict__ G2T, const float* __restrict__ bm,
                       const short* __restrict__ W2T, short* __restrict__ Dt,
                       int e0, int EC) {
  __shared__ __align__(16) short SMEM[65536];    // 128 KB
  short* As0 = SMEM;            // [2][16384]
  short* Bs0 = SMEM + 32768;    // [2][16384]

  const int tid = threadIdx.x;
  const int lane = tid & 63, wid = tid >> 6;
  const int wm = wid >> 2, wn = wid & 3;
  const int fr = lane & 15, fq = lane >> 4;
  const int m0 = blockIdx.y * 256;
  const int n0 = blockIdx.x * 256;       // = batch bx * 256
  const size_t arow0 = (size_t)(e0 + m0) * 1024;

  const int rl = tid >> 3;
  const int ce = ((tid & 7) ^ (rl & 7)) << 3;
  const int ldst = wid << 9;

  f32x4 acc[8][4] = {};

  auto stageA = [&](int buf, int kt, int iss) {
    const short* s = (kt < 1024 ? Ain : Aout) + arow0
                   + (size_t)(iss * 64 + rl) * 1024 + (kt & 1023) + ce;
    glds16(&As0[buf * 16384 + iss * 4096 + ldst], s);
  };
  auto stageB = [&](int buf, int kt, int iss) {
    const short* s = G2T + (size_t)(n0 + iss * 64 + rl) * 2048 + kt + ce;
    glds16(&Bs0[buf * 16384 + iss * 4096 + ldst], s);
  };

#define EG_PHASE(QM, QN, STAGES, WAITOP)                                          \
  {                                                                               \
    bf16x8 af[4][2], bv[2][2];                                                    \
    _Pragma("unroll")                                                             \
    for (int i = 0; i < 4; ++i) {                                                 \
      int r = wm * 128 + ((QM) * 4 + i) * 16 + fr;                                \
      _Pragma("unroll")                                                           \
      for (int s = 0; s < 2; ++s)                                                 \
        af[i][s] = *(const bf16x8*)&As0[buf * 16384 + r * 64 + (((s * 4 + fq) ^ (r & 7)) << 3)]; \
    }                                                                             \
    _Pragma("unroll")                                                             \
    for (int j = 0; j < 2; ++j) {                                                 \
      int rb = wn * 64 + ((QN) * 2 + j) * 16 + fr;                                \
      _Pragma("unroll")                                                           \
      for (int s = 0; s < 2; ++s)                                                 \
        bv[j][s] = *(const bf16x8*)&Bs0[buf * 16384 + rb * 64 + (((s * 4 + fq) ^ (rb & 7)) << 3)]; \
    }                                                                             \
    STAGES                                                                        \
    WAITOP                                                                        \
    BAR();                                                                        \
    asm volatile("s_waitcnt lgkmcnt(0)" ::: "memory");                            \
    __builtin_amdgcn_s_setprio(1);                                                \
    _Pragma("unroll")                                                             \
    for (int i = 0; i < 4; ++i)                                                   \
      _Pragma("unroll")                                                           \
      for (int j = 0; j < 2; ++j) {                                               \
        acc[(QM) * 4 + i][(QN) * 2 + j] = __builtin_amdgcn_mfma_f32_16x16x32_bf16(\
            af[i][0], bv[j][0], acc[(QM) * 4 + i][(QN) * 2 + j], 0, 0, 0);        \
        acc[(QM) * 4 + i][(QN) * 2 + j] = __builtin_amdgcn_mfma_f32_16x16x32_bf16(\
            af[i][1], bv[j][1], acc[(QM) * 4 + i][(QN) * 2 + j], 0, 0, 0);        \
      }                                                                           \
    __builtin_amdgcn_s_setprio(0);                                                \
    BAR();                                                                        \
  }

  #pragma unroll
  for (int i = 0; i < 4; ++i) stageA(0, 0, i);
  #pragma unroll
  for (int i = 0; i < 4; ++i) stageB(0, 0, i);
  asm volatile("s_waitcnt vmcnt(0)" ::: "memory");
  BAR();

  constexpr int NT = 2048 / 64;
  for (int t = 0; t < NT; ++t) {
    const int buf = t & 1, nb = buf ^ 1, ktn = (t + 1) * 64;
    const bool pre = (t + 1 < NT);
    EG_PHASE(0, 0, { if (pre) { stageA(nb, ktn, 0); stageA(nb, ktn, 2); } }, ;)
    EG_PHASE(0, 1, { if (pre) { stageB(nb, ktn, 0); stageB(nb, ktn, 1); } },
             asm volatile("s_waitcnt vmcnt(4)" ::: "memory");)
    EG_PHASE(1, 0, { if (pre) { stageB(nb, ktn, 2); stageB(nb, ktn, 3); } }, ;)
    EG_PHASE(1, 1, { if (pre) { stageA(nb, ktn, 1); stageA(nb, ktn, 3); } },
             asm volatile("s_waitcnt vmcnt(2)" ::: "memory");)
  }
#undef EG_PHASE

  // ---- fused D epilogue ----------------------------------------------
  #pragma unroll
  for (int i = 0; i < 8; ++i) {
    int eb = wm * 128 + i * 16 + fq * 4;
    #pragma unroll
    for (int j = 0; j < 4; ++j) {
      int f = wn * 64 + j * 16 + fr;
      float bb = bm[f];
      #pragma unroll
      for (int r = 0; r < 4; ++r) {
        int er = eb + r;
        SMEM[er * 256 + ((((f >> 3) ^ (er & 7)) << 3) | (f & 7))] =
            f2bf(fmaxf(acc[i][j][r] + bb, 0.0f));
      }
    }
  }
  asm volatile("s_waitcnt lgkmcnt(0)" ::: "memory");
  BAR();
  bf16x8 w2f[2][8];
  #pragma unroll
  for (int jj = 0; jj < 2; ++jj) {
    int row = wn * 32 + jj * 16 + fr;
    #pragma unroll
    for (int kk = 0; kk < 8; ++kk)
      w2f[jj][kk] = *(const bf16x8*)(W2T + (size_t)row * 256 + kk * 32 + fq * 8);
  }
  f32x4 dacc[8][2] = {};
  #pragma unroll
  for (int kk = 0; kk < 8; ++kk) {
    #pragma unroll
    for (int ii = 0; ii < 8; ++ii) {
      int er = wm * 128 + ii * 16 + fr;
      bf16x8 a = *(const bf16x8*)&SMEM[er * 256 + (((kk * 4 + fq) ^ (er & 7)) << 3)];
      dacc[ii][0] = __builtin_amdgcn_mfma_f32_16x16x32_bf16(a, w2f[0][kk], dacc[ii][0], 0, 0, 0);
      dacc[ii][1] = __builtin_amdgcn_mfma_f32_16x16x32_bf16(a, w2f[1][kk], dacc[ii][1], 0, 0, 0);
    }
  }
  const int bx = blockIdx.x;
  #pragma unroll
  for (int ii = 0; ii < 8; ++ii) {
    int e = m0 + wm * 128 + ii * 16 + fq * 4;
    #pragma unroll
    for (int jj = 0; jj < 2; ++jj) {
      int frow = bx * 128 + wn * 32 + jj * 16 + fr;
      short4 pk;
      pk.x = f2bf(dacc[ii][jj][0]);
      pk.y = f2bf(dacc[ii][jj][1]);
      pk.z = f2bf(dacc[ii][jj][2]);
      pk.w = f2bf(dacc[ii][jj][3]);
      *(short4*)&Dt[(size_t)frow * EC + e] = pk;
    }
  }
}

// ---- launch --------------------------------------------------------------
extern "C" void kernel_launch(void* const* d_in, const int* in_sizes, int n_in,
                              void* d_out, int out_size, void* d_ws, size_t ws_size,
                              hipStream_t stream) {
  const float* x     = (const float*)d_in[0];
  const int*   ei    = (const int*)d_in[1];
  const float* m_in  = (const float*)d_in[2];
  const float* m_out = (const float*)d_in[3];
  const float* W1    = (const float*)d_in[4];
  const float* b1    = (const float*)d_in[5];
  const float* Wm    = (const float*)d_in[6];
  const float* bm    = (const float*)d_in[7];
  const float* W2    = (const float*)d_in[8];
  const float* b2    = (const float*)d_in[9];
  float* out = (float*)d_out;
  const int* src = ei;
  const int* dst = ei + NE;

  char* w = (char*)d_ws;
  size_t used = 0;
  auto alloc = [&](size_t bytes) {
    char* p = w; size_t r = (bytes + 255) & ~(size_t)255;
    w += r; used += r; return p;
  };
  int*   deg    = (int*)  alloc((size_t)NN * 4);
  short* Adjb   = (short*)alloc((size_t)NN * NN * 2);        // 2 MB
  short* W1T    = (short*)alloc((size_t)FH * FIN * 2);
  short* WmT    = (short*)alloc((size_t)2 * FH * FH * 2);
  short* W2T    = (short*)alloc((size_t)FOUT * FH * 2);
  short* G2T    = (short*)alloc((size_t)2048 * 2048 * 2);    // 8 MB [(b,f)][(h,node)]
  float* H2X    = (float*)alloc((size_t)NN * 1024 * 4);      // 4 MB [node][(b,f128)]
  short* m_in_bf  = (short*)alloc((size_t)NE * NN * 2);      // 64 MB
  short* m_out_bf = (short*)alloc((size_t)NE * NN * 2);      // 64 MB
  short* m_inT    = (short*)alloc((size_t)NN * NE * 2);      // 64 MB [1024][32768]

  // union region U: {Adj,XW1T,Hb} -> {Dt} -> {XW2T}
  int EC = 4096;
  for (int ec : {32768, 16384, 8192}) {
    size_t need = (size_t)ec * 2048;   // Dt = ec*1024*2 bytes
    if (need < (12u << 20)) need = 12u << 20;
    if (used + need + (1u << 20) <= ws_size) { EC = ec; break; }
  }
  size_t ubytes = (size_t)EC * 2048;
  if (ubytes < (12u << 20)) ubytes = 12u << 20;
  char* U = alloc(ubytes);
  float* Adj  = (float*)U;                        // 4 MB   (early)
  short* XW1T = (short*)(U + (4u << 20));         // 4 MB   (early) [256][8192]
  short* Hb   = (short*)(U + (8u << 20));         // 4 MB   (early) [8192][256]
  short* Dt   = (short*)U;                        // EC*1024*2 (mid) [1024][EC]
  short* XW2T = (short*)U;                        // 2 MB   (late)  [128][8192]

  const int nchunk = NE / EC;
  const int nsplit = (EC >= 16384) ? 16 : 8;

  hipMemsetAsync(deg, 0, (size_t)NN * 4, stream);
  hipMemsetAsync(Adj, 0, (size_t)NN * NN * 4, stream);
  hipMemsetAsync(H2X, 0, (size_t)NN * 1024 * 4, stream);

  k_deg<<<(NE + 255) / 256, 256, 0, stream>>>(dst, deg);
  k_adj<<<(NE + NN + 255) / 256, 256, 0, stream>>>(src, dst, deg, Adj);
  k_cast<<<NN * NN / 4 / 256, 256, 0, stream>>>((const float4*)Adj, Adjb);

  k_wt<<<(128 * 256 + 512 * 256 + 256 * 128) / 256, 256, 0, stream>>>(
      W1, Wm, W2, W1T, WmT, W2T);
  k_prep<<<dim3(NE / 64, NN / 64, 2), 256, 0, stream>>>(
      m_in, m_out, m_in_bf, m_out_bf, m_inT);

  // XW1T = (x @ W1)^T  bf16 [256][8192]
  gemm_mfma<0, 2, 0, false, false><<<dim3(2, 64, 1), 256, 0, stream>>>(
      nullptr, x, W1T, nullptr, XW1T, FIN, FIN, MR, FIN, 0, 1, 0, 0, 0, 0, 0, 1.0f);

  // Hb = relu(Adjb @ XW1_b + b1)  bf16 [8192][256]
  gemm_mfma<2, 0, 1, true, true><<<dim3(2, 8, NB), 256, 0, stream>>>(
      Adjb, nullptr, XW1T, b1, Hb,
      NN, 0, FH, NN, 0, 1, 1024, 0, 0, (size_t)NN * FH, 0, 1.0f);

  // G2T[(b,f)][(h,node)] = sum_c WmT[h][f][c] * Hb[b][node][c]
  gemm_mfma<2, 0, 0, false, false><<<dim3(8, 2, 16), 256, 0, stream>>>(
      WmT, nullptr, Hb, nullptr, G2T,
      FH, FH, 2048, FH, 0, 2, 0,
      (size_t)FH * FH, (size_t)NN * FH, (size_t)FH * 2048, 1024, 1.0f);

  for (int c = 0; c < nchunk; ++c) {
    // Dt[(b,f128)][e] = relu([m_in|m_out] @ G2T^T + bm) @ W2  (fused)
    egemm8<<<dim3(8, EC / 256, 1), 512, 0, stream>>>(
        m_in_bf, m_out_bf, G2T, bm, W2T, Dt, c * EC, EC);
    // H2X += m_inT_chunk @ Dt^T  fp32 atomics, split-K (/1024 folded later)
    gemm_mfma<1, 0, 0, false, false><<<dim3(8, 8, nsplit), 256, 0, stream>>>(
        m_inT + (size_t)c * EC, nullptr, Dt, nullptr, H2X,
        32768, EC, 1024, EC, EC / nsplit, 1, 0, 0, 0, 0, 0, 1.0f);
  }

  // XW2T[f128][(b,node)] = bf16(H2X / 1024)
  k_repack2<<<dim3(32, 32), 256, 0, stream>>>(H2X, XW2T);

  // out_b = Adjb @ XW2_b + b2  fp32 [8192][128]
  gemm_mfma<3, 0, 1, true, false><<<dim3(1, 8, NB), 256, 0, stream>>>(
      Adjb, nullptr, XW2T, b2, out,
      NN, 0, FOUT, NN, 0, 1, 1024, 0, 0, (size_t)NN * FOUT, 0, 1.0f);
}

// Round 16
// 609.938 us; speedup vs baseline: 1.0089x; 1.0089x over previous
//
#include <hip/hip_runtime.h>
#include <hip/hip_bf16.h>

typedef __attribute__((ext_vector_type(8))) short bf16x8;
typedef __attribute__((ext_vector_type(4))) float f32x4;

static constexpr int NB   = 8;
static constexpr int NN   = 1024;
static constexpr int NE   = 32768;
static constexpr int FIN  = 128;
static constexpr int FH   = 256;
static constexpr int FOUT = 128;
static constexpr int MR   = NB * NN;

__device__ __forceinline__ short f2bf(float f) {
  union { __hip_bfloat16 h; short s; } u;
  u.h = __float2bfloat16(f);
  return u.s;
}

typedef const __attribute__((address_space(1))) void gas_void;
typedef __attribute__((address_space(3))) void las_void;
__device__ __forceinline__ void glds16(short* lds, const short* g) {
  __builtin_amdgcn_global_load_lds((gas_void*)g, (las_void*)lds, 16, 0, 0);
}
__device__ __forceinline__ void BAR() {
  asm volatile("" ::: "memory");
  __builtin_amdgcn_s_barrier();
  asm volatile("" ::: "memory");
}

// ---- graph preprocessing -------------------------------------------------
__global__ void k_deg(const int* __restrict__ dst, int* __restrict__ deg) {
  int e = blockIdx.x * blockDim.x + threadIdx.x;
  if (e < NE) atomicAdd(&deg[dst[e]], 1);
}
__global__ void k_adj(const int* __restrict__ src, const int* __restrict__ dst,
                      const int* __restrict__ deg, float* __restrict__ Adj) {
  int t = blockIdx.x * blockDim.x + threadIdx.x;
  if (t < NE) {
    int s = src[t], d = dst[t];
    float ds = rsqrtf((float)(deg[s] + 1));
    float dd = rsqrtf((float)(deg[d] + 1));
    atomicAdd(&Adj[d * NN + s], ds * dd);
  } else if (t < NE + NN) {
    int n = t - NE;
    float dn = rsqrtf((float)(deg[n] + 1));
    atomicAdd(&Adj[n * NN + n], dn * dn);
  }
}

// ---- layout / cast kernels ----------------------------------------------
__global__ __launch_bounds__(256) void k_cast(const float4* __restrict__ S,
                                              short* __restrict__ D) {
  size_t q = (size_t)blockIdx.x * 256 + threadIdx.x;
  float4 a = S[q];
  short4 p;
  p.x = f2bf(a.x); p.y = f2bf(a.y); p.z = f2bf(a.z); p.w = f2bf(a.w);
  *(short4*)&D[q * 4] = p;
}
__global__ __launch_bounds__(256) void k_wt(const float* __restrict__ W1,
                                            const float* __restrict__ Wm,
                                            const float* __restrict__ W2,
                                            short* __restrict__ W1T,
                                            short* __restrict__ WmT,
                                            short* __restrict__ W2T) {
  int idx = blockIdx.x * 256 + threadIdx.x;
  if (idx < 128 * 256) {
    int r = idx >> 8, c = idx & 255;
    W1T[c * 128 + r] = f2bf(W1[idx]);
  } else if (idx < 128 * 256 + 512 * 256) {
    int k = idx - 128 * 256;
    int r = k >> 8, c = k & 255;
    int h = r >> 8, kk = r & 255;
    WmT[h * 65536 + c * 256 + kk] = f2bf(Wm[k]);
  } else {
    int k = idx - 128 * 256 - 512 * 256;
    int r = k >> 7, c = k & 127;
    W2T[c * 256 + r] = f2bf(W2[k]);
  }
}
// z=0: m_in -> mi_bf (vectorized) + miT (tile transpose); z=1: m_out -> mo_bf
__global__ __launch_bounds__(256) void k_prep(const float* __restrict__ mi,
                                              const float* __restrict__ mo,
                                              short* __restrict__ mi_bf,
                                              short* __restrict__ mo_bf,
                                              short* __restrict__ miT) {
  int tid = threadIdx.x;
  int e0 = blockIdx.x * 64, n0 = blockIdx.y * 64;
  if (blockIdx.z == 1) {
    #pragma unroll
    for (int it = 0; it < 4; ++it) {
      int r = it * 16 + (tid >> 4);
      int c4 = (tid & 15) * 4;
      float4 v = *(const float4*)&mo[(size_t)(e0 + r) * 1024 + n0 + c4];
      short4 p;
      p.x = f2bf(v.x); p.y = f2bf(v.y); p.z = f2bf(v.z); p.w = f2bf(v.w);
      *(short4*)&mo_bf[(size_t)(e0 + r) * 1024 + n0 + c4] = p;
    }
    return;
  }
  __shared__ short tile[64][71];
  #pragma unroll
  for (int it = 0; it < 4; ++it) {
    int r = it * 16 + (tid >> 4);
    int c4 = (tid & 15) * 4;
    float4 v = *(const float4*)&mi[(size_t)(e0 + r) * 1024 + n0 + c4];
    short4 p;
    p.x = f2bf(v.x); p.y = f2bf(v.y); p.z = f2bf(v.z); p.w = f2bf(v.w);
    *(short4*)&mi_bf[(size_t)(e0 + r) * 1024 + n0 + c4] = p;
    tile[c4 + 0][r] = p.x;
    tile[c4 + 1][r] = p.y;
    tile[c4 + 2][r] = p.z;
    tile[c4 + 3][r] = p.w;
  }
  __syncthreads();
  int n = tid >> 2, ec = (tid & 3) * 16;
  #pragma unroll
  for (int q = 0; q < 4; ++q) {
    short4 v;
    v.x = tile[n][ec + q * 4 + 0];
    v.y = tile[n][ec + q * 4 + 1];
    v.z = tile[n][ec + q * 4 + 2];
    v.w = tile[n][ec + q * 4 + 3];
    *(short4*)&miT[(size_t)(n0 + n) * 32768 + e0 + ec + q * 4] = v;
  }
}
// XW2T[f128][(b,node)] = bf16(H2X[node][b*128+f128] / 1024)  (tiled transpose)
__global__ __launch_bounds__(256) void k_repack2(const float* __restrict__ H2X,
                                                 short* __restrict__ XW2T) {
  __shared__ float t[32][33];
  int n0 = blockIdx.x * 32, c0 = blockIdx.y * 32;
  int r = threadIdx.x >> 5, cc = threadIdx.x & 31;
  #pragma unroll
  for (int p = 0; p < 4; ++p)
    t[r + p * 8][cc] = H2X[(size_t)(n0 + r + p * 8) * 1024 + c0 + cc];
  __syncthreads();
  const float inv = 1.0f / 1024.0f;
  #pragma unroll
  for (int p = 0; p < 4; ++p) {
    int c = c0 + r + p * 8;
    int b = c >> 7, f = c & 127;
    XW2T[(size_t)f * 8192 + b * 1024 + n0 + cc] = f2bf(t[cc][r + p * 8] * inv);
  }
}

// ---- proven 128x128 bf16 MFMA GEMM: C = A[M,K] @ BT[N,K]^T ---------------
template <int EPI, int ASRC, int BSEL, bool BIAS, bool RELU>
__launch_bounds__(256)
__global__ void gemm_mfma(const short* __restrict__ Ab, const float* __restrict__ Af,
                          const short* __restrict__ BT, const float* __restrict__ bias,
                          void* __restrict__ Cv,
                          int lda, int ldb, int ldc, int K, int kSplit, int nz2,
                          int zcolB, size_t szA, size_t szB, size_t szC, size_t szC2,
                          float scale) {
  __shared__ __align__(16) short As[128 * 64];
  __shared__ __align__(16) short Bs[128 * 64];

  const int tid = threadIdx.x;
  const int lane = tid & 63, wid = tid >> 6;
  const int wr = wid >> 1, wc = wid & 1;
  const int fr = lane & 15, fq = lane >> 4;
  const int m0 = blockIdx.y * 128, n0 = blockIdx.x * 128;

  int zA = 0, zB = 0, k0 = 0, k1 = K;
  if constexpr (EPI == 1) {
    k0 = blockIdx.z * kSplit; k1 = k0 + kSplit;
  } else {
    zA = (int)blockIdx.z % nz2; zB = (int)blockIdx.z / nz2;
  }
  if constexpr (ASRC == 0) Ab += (size_t)zA * szA;
  else                     Af += (size_t)zA * szA;
  BT += (size_t)zB * szB;
  const int colB = zB * zcolB;

  const int rq = lane >> 3;
  const int ks = (lane & 7) ^ rq;

  f32x4 acc[4][4] = {};

  for (int kt = k0; kt < k1; kt += 64) {
    if constexpr (ASRC == 2) {
      #pragma unroll
      for (int p = 0; p < 4; ++p) {
        int i = p * 256 + tid, row = i >> 3, g = i & 7;
        const float* ap = Af + (size_t)(m0 + row) * lda + kt + g * 8;
        bf16x8 v;
        #pragma unroll
        for (int e = 0; e < 8; ++e) v[e] = f2bf(ap[e]);
        *(bf16x8*)&As[row * 64 + ((g ^ (row & 7)) * 8)] = v;
      }
    } else {
      #pragma unroll
      for (int c = 0; c < 4; ++c) {
        int row = wid * 32 + c * 8 + rq;
        glds16(&As[(wid * 256 + c * 64) * 8],
               Ab + (size_t)(m0 + row) * lda + kt + ks * 8);
      }
    }
    {
      const short* Bsrc;
      int ldbe;
      if constexpr (BSEL == 1) { Bsrc = BT + colB; ldbe = 8192; }
      else                     { Bsrc = BT;        ldbe = ldb;  }
      #pragma unroll
      for (int c = 0; c < 4; ++c) {
        int row = wid * 32 + c * 8 + rq;
        glds16(&Bs[(wid * 256 + c * 64) * 8],
               Bsrc + (size_t)(n0 + row) * ldbe + kt + ks * 8);
      }
    }
    __syncthreads();
    bf16x8 afv[4][2], bfv[4][2];
    #pragma unroll
    for (int i = 0; i < 4; ++i) {
      int row = wr * 64 + i * 16 + fr;
      #pragma unroll
      for (int kh = 0; kh < 2; ++kh)
        afv[i][kh] = *(const bf16x8*)&As[row * 64 + (((kh * 4 + fq) ^ (fr & 7)) * 8)];
    }
    #pragma unroll
    for (int j = 0; j < 4; ++j) {
      int row = wc * 64 + j * 16 + fr;
      #pragma unroll
      for (int kh = 0; kh < 2; ++kh)
        bfv[j][kh] = *(const bf16x8*)&Bs[row * 64 + (((kh * 4 + fq) ^ (fr & 7)) * 8)];
    }
    #pragma unroll
    for (int i = 0; i < 4; ++i)
      #pragma unroll
      for (int j = 0; j < 4; ++j) {
        acc[i][j] = __builtin_amdgcn_mfma_f32_16x16x32_bf16(afv[i][0], bfv[j][0], acc[i][j], 0, 0, 0);
        acc[i][j] = __builtin_amdgcn_mfma_f32_16x16x32_bf16(afv[i][1], bfv[j][1], acc[i][j], 0, 0, 0);
      }
    __syncthreads();
  }

  const size_t cOff = (size_t)zB * szC + (size_t)zA * szC2;
  #pragma unroll
  for (int i = 0; i < 4; ++i) {
    int rowb = m0 + wr * 64 + i * 16 + fq * 4;
    #pragma unroll
    for (int j = 0; j < 4; ++j) {
      int col = n0 + wc * 64 + j * 16 + fr;
      float bv = 0.0f;
      if constexpr (BIAS) bv = bias[col];
      float v0 = acc[i][j][0] + bv, v1 = acc[i][j][1] + bv;
      float v2 = acc[i][j][2] + bv, v3 = acc[i][j][3] + bv;
      if constexpr (RELU) {
        v0 = fmaxf(v0, 0.0f); v1 = fmaxf(v1, 0.0f);
        v2 = fmaxf(v2, 0.0f); v3 = fmaxf(v3, 0.0f);
      }
      if constexpr (EPI == 0) {
        short* Ct = (short*)Cv + cOff;
        short4 pk;
        pk.x = f2bf(v0); pk.y = f2bf(v1); pk.z = f2bf(v2); pk.w = f2bf(v3);
        *(short4*)(Ct + (size_t)col * ldc + rowb) = pk;
      } else if constexpr (EPI == 1) {
        float* Cf = (float*)Cv;
        atomicAdd(&Cf[(size_t)(rowb + 0) * ldc + col], acc[i][j][0] * scale);
        atomicAdd(&Cf[(size_t)(rowb + 1) * ldc + col], acc[i][j][1] * scale);
        atomicAdd(&Cf[(size_t)(rowb + 2) * ldc + col], acc[i][j][2] * scale);
        atomicAdd(&Cf[(size_t)(rowb + 3) * ldc + col], acc[i][j][3] * scale);
      } else if constexpr (EPI == 2) {
        short* Cn = (short*)Cv + cOff;
        Cn[(size_t)(rowb + 0) * ldc + col] = f2bf(v0);
        Cn[(size_t)(rowb + 1) * ldc + col] = f2bf(v1);
        Cn[(size_t)(rowb + 2) * ldc + col] = f2bf(v2);
        Cn[(size_t)(rowb + 3) * ldc + col] = f2bf(v3);
      } else {
        float* Cf = (float*)Cv + cOff;
        Cf[(size_t)(rowb + 0) * ldc + col] = v0;
        Cf[(size_t)(rowb + 1) * ldc + col] = v1;
        Cf[(size_t)(rowb + 2) * ldc + col] = v2;
        Cf[(size_t)(rowb + 3) * ldc + col] = v3;
      }
    }
  }
}

// ---- 8-phase 256x256 edge GEMM + FUSED D epilogue ------------------------
// Grid TRANSPOSED: bx = e-row tile, by = column band (batch). Linear block id
// = by*(EC/256)+bx with (EC/256)%8==0 -> xcd = bx%8: the 8 blocks sharing one
// A-panel land on the SAME XCD (one L2 fill) and A stays L3-resident.
__launch_bounds__(512, 2)
__global__ void egemm8(const short* __restrict__ Ain, const short* __restrict__ Aout,
                       const short* __restrict__ G2T, const float* __restrict__ bm,
                       const short* __restrict__ W2T, short* __restrict__ Dt,
                       int e0, int EC) {
  __shared__ __align__(16) short SMEM[65536];    // 128 KB
  short* As0 = SMEM;            // [2][16384]
  short* Bs0 = SMEM + 32768;    // [2][16384]

  const int tid = threadIdx.x;
  const int lane = tid & 63, wid = tid >> 6;
  const int wm = wid >> 2, wn = wid & 3;
  const int fr = lane & 15, fq = lane >> 4;
  const int m0 = blockIdx.x * 256;       // e-row tile
  const int n0 = blockIdx.y * 256;       // column band = batch by * 256
  const size_t arow0 = (size_t)(e0 + m0) * 1024;

  const int rl = tid >> 3;
  const int ce = ((tid & 7) ^ (rl & 7)) << 3;
  const int ldst = wid << 9;

  f32x4 acc[8][4] = {};

  auto stageA = [&](int buf, int kt, int iss) {
    const short* s = (kt < 1024 ? Ain : Aout) + arow0
                   + (size_t)(iss * 64 + rl) * 1024 + (kt & 1023) + ce;
    glds16(&As0[buf * 16384 + iss * 4096 + ldst], s);
  };
  auto stageB = [&](int buf, int kt, int iss) {
    const short* s = G2T + (size_t)(n0 + iss * 64 + rl) * 2048 + kt + ce;
    glds16(&Bs0[buf * 16384 + iss * 4096 + ldst], s);
  };

#define EG_PHASE(QM, QN, STAGES, WAITOP)                                          \
  {                                                                               \
    bf16x8 af[4][2], bv[2][2];                                                    \
    _Pragma("unroll")                                                             \
    for (int i = 0; i < 4; ++i) {                                                 \
      int r = wm * 128 + ((QM) * 4 + i) * 16 + fr;                                \
      _Pragma("unroll")                                                           \
      for (int s = 0; s < 2; ++s)                                                 \
        af[i][s] = *(const bf16x8*)&As0[buf * 16384 + r * 64 + (((s * 4 + fq) ^ (r & 7)) << 3)]; \
    }                                                                             \
    _Pragma("unroll")                                                             \
    for (int j = 0; j < 2; ++j) {                                                 \
      int rb = wn * 64 + ((QN) * 2 + j) * 16 + fr;                                \
      _Pragma("unroll")                                                           \
      for (int s = 0; s < 2; ++s)                                                 \
        bv[j][s] = *(const bf16x8*)&Bs0[buf * 16384 + rb * 64 + (((s * 4 + fq) ^ (rb & 7)) << 3)]; \
    }                                                                             \
    STAGES                                                                        \
    WAITOP                                                                        \
    BAR();                                                                        \
    asm volatile("s_waitcnt lgkmcnt(0)" ::: "memory");                            \
    __builtin_amdgcn_s_setprio(1);                                                \
    _Pragma("unroll")                                                             \
    for (int i = 0; i < 4; ++i)                                                   \
      _Pragma("unroll")                                                           \
      for (int j = 0; j < 2; ++j) {                                               \
        acc[(QM) * 4 + i][(QN) * 2 + j] = __builtin_amdgcn_mfma_f32_16x16x32_bf16(\
            af[i][0], bv[j][0], acc[(QM) * 4 + i][(QN) * 2 + j], 0, 0, 0);        \
        acc[(QM) * 4 + i][(QN) * 2 + j] = __builtin_amdgcn_mfma_f32_16x16x32_bf16(\
            af[i][1], bv[j][1], acc[(QM) * 4 + i][(QN) * 2 + j], 0, 0, 0);        \
      }                                                                           \
    __builtin_amdgcn_s_setprio(0);                                                \
    BAR();                                                                        \
  }

  #pragma unroll
  for (int i = 0; i < 4; ++i) stageA(0, 0, i);
  #pragma unroll
  for (int i = 0; i < 4; ++i) stageB(0, 0, i);
  asm volatile("s_waitcnt vmcnt(0)" ::: "memory");
  BAR();

  constexpr int NT = 2048 / 64;
  for (int t = 0; t < NT; ++t) {
    const int buf = t & 1, nb = buf ^ 1, ktn = (t + 1) * 64;
    const bool pre = (t + 1 < NT);
    EG_PHASE(0, 0, { if (pre) { stageA(nb, ktn, 0); stageA(nb, ktn, 2); } }, ;)
    EG_PHASE(0, 1, { if (pre) { stageB(nb, ktn, 0); stageB(nb, ktn, 1); } },
             asm volatile("s_waitcnt vmcnt(4)" ::: "memory");)
    EG_PHASE(1, 0, { if (pre) { stageB(nb, ktn, 2); stageB(nb, ktn, 3); } }, ;)
    EG_PHASE(1, 1, { if (pre) { stageA(nb, ktn, 1); stageA(nb, ktn, 3); } },
             asm volatile("s_waitcnt vmcnt(2)" ::: "memory");)
  }
#undef EG_PHASE

  // ---- fused D epilogue ----------------------------------------------
  #pragma unroll
  for (int i = 0; i < 8; ++i) {
    int eb = wm * 128 + i * 16 + fq * 4;
    #pragma unroll
    for (int j = 0; j < 4; ++j) {
      int f = wn * 64 + j * 16 + fr;
      float bb = bm[f];
      #pragma unroll
      for (int r = 0; r < 4; ++r) {
        int er = eb + r;
        SMEM[er * 256 + ((((f >> 3) ^ (er & 7)) << 3) | (f & 7))] =
            f2bf(fmaxf(acc[i][j][r] + bb, 0.0f));
      }
    }
  }
  asm volatile("s_waitcnt lgkmcnt(0)" ::: "memory");
  BAR();
  bf16x8 w2f[2][8];
  #pragma unroll
  for (int jj = 0; jj < 2; ++jj) {
    int row = wn * 32 + jj * 16 + fr;
    #pragma unroll
    for (int kk = 0; kk < 8; ++kk)
      w2f[jj][kk] = *(const bf16x8*)(W2T + (size_t)row * 256 + kk * 32 + fq * 8);
  }
  f32x4 dacc[8][2] = {};
  #pragma unroll
  for (int kk = 0; kk < 8; ++kk) {
    #pragma unroll
    for (int ii = 0; ii < 8; ++ii) {
      int er = wm * 128 + ii * 16 + fr;
      bf16x8 a = *(const bf16x8*)&SMEM[er * 256 + (((kk * 4 + fq) ^ (er & 7)) << 3)];
      dacc[ii][0] = __builtin_amdgcn_mfma_f32_16x16x32_bf16(a, w2f[0][kk], dacc[ii][0], 0, 0, 0);
      dacc[ii][1] = __builtin_amdgcn_mfma_f32_16x16x32_bf16(a, w2f[1][kk], dacc[ii][1], 0, 0, 0);
    }
  }
  const int bcol = blockIdx.y;           // batch index (column band)
  #pragma unroll
  for (int ii = 0; ii < 8; ++ii) {
    int e = m0 + wm * 128 + ii * 16 + fq * 4;
    #pragma unroll
    for (int jj = 0; jj < 2; ++jj) {
      int frow = bcol * 128 + wn * 32 + jj * 16 + fr;
      short4 pk;
      pk.x = f2bf(dacc[ii][jj][0]);
      pk.y = f2bf(dacc[ii][jj][1]);
      pk.z = f2bf(dacc[ii][jj][2]);
      pk.w = f2bf(dacc[ii][jj][3]);
      *(short4*)&Dt[(size_t)frow * EC + e] = pk;
    }
  }
}

// ---- launch --------------------------------------------------------------
extern "C" void kernel_launch(void* const* d_in, const int* in_sizes, int n_in,
                              void* d_out, int out_size, void* d_ws, size_t ws_size,
                              hipStream_t stream) {
  const float* x     = (const float*)d_in[0];
  const int*   ei    = (const int*)d_in[1];
  const float* m_in  = (const float*)d_in[2];
  const float* m_out = (const float*)d_in[3];
  const float* W1    = (const float*)d_in[4];
  const float* b1    = (const float*)d_in[5];
  const float* Wm    = (const float*)d_in[6];
  const float* bm    = (const float*)d_in[7];
  const float* W2    = (const float*)d_in[8];
  const float* b2    = (const float*)d_in[9];
  float* out = (float*)d_out;
  const int* src = ei;
  const int* dst = ei + NE;

  char* w = (char*)d_ws;
  size_t used = 0;
  auto alloc = [&](size_t bytes) {
    char* p = w; size_t r = (bytes + 255) & ~(size_t)255;
    w += r; used += r; return p;
  };
  int*   deg    = (int*)  alloc((size_t)NN * 4);
  short* Adjb   = (short*)alloc((size_t)NN * NN * 2);        // 2 MB
  short* W1T    = (short*)alloc((size_t)FH * FIN * 2);
  short* WmT    = (short*)alloc((size_t)2 * FH * FH * 2);
  short* W2T    = (short*)alloc((size_t)FOUT * FH * 2);
  short* G2T    = (short*)alloc((size_t)2048 * 2048 * 2);    // 8 MB [(b,f)][(h,node)]
  float* H2X    = (float*)alloc((size_t)NN * 1024 * 4);      // 4 MB [node][(b,f128)]
  short* m_in_bf  = (short*)alloc((size_t)NE * NN * 2);      // 64 MB
  short* m_out_bf = (short*)alloc((size_t)NE * NN * 2);      // 64 MB
  short* m_inT    = (short*)alloc((size_t)NN * NE * 2);      // 64 MB [1024][32768]

  // union region U: {Adj,XW1T,Hb} -> {Dt} -> {XW2T}
  int EC = 4096;
  for (int ec : {32768, 16384, 8192}) {
    size_t need = (size_t)ec * 2048;   // Dt = ec*1024*2 bytes
    if (need < (12u << 20)) need = 12u << 20;
    if (used + need + (1u << 20) <= ws_size) { EC = ec; break; }
  }
  size_t ubytes = (size_t)EC * 2048;
  if (ubytes < (12u << 20)) ubytes = 12u << 20;
  char* U = alloc(ubytes);
  float* Adj  = (float*)U;                        // 4 MB   (early)
  short* XW1T = (short*)(U + (4u << 20));         // 4 MB   (early) [256][8192]
  short* Hb   = (short*)(U + (8u << 20));         // 4 MB   (early) [8192][256]
  short* Dt   = (short*)U;                        // EC*1024*2 (mid) [1024][EC]
  short* XW2T = (short*)U;                        // 2 MB   (late)  [128][8192]

  const int nchunk = NE / EC;
  const int nsplit = (EC >= 16384) ? 16 : 8;

  hipMemsetAsync(deg, 0, (size_t)NN * 4, stream);
  hipMemsetAsync(Adj, 0, (size_t)NN * NN * 4, stream);
  hipMemsetAsync(H2X, 0, (size_t)NN * 1024 * 4, stream);

  k_deg<<<(NE + 255) / 256, 256, 0, stream>>>(dst, deg);
  k_adj<<<(NE + NN + 255) / 256, 256, 0, stream>>>(src, dst, deg, Adj);
  k_cast<<<NN * NN / 4 / 256, 256, 0, stream>>>((const float4*)Adj, Adjb);

  k_wt<<<(128 * 256 + 512 * 256 + 256 * 128) / 256, 256, 0, stream>>>(
      W1, Wm, W2, W1T, WmT, W2T);
  k_prep<<<dim3(NE / 64, NN / 64, 2), 256, 0, stream>>>(
      m_in, m_out, m_in_bf, m_out_bf, m_inT);

  // XW1T = (x @ W1)^T  bf16 [256][8192]
  gemm_mfma<0, 2, 0, false, false><<<dim3(2, 64, 1), 256, 0, stream>>>(
      nullptr, x, W1T, nullptr, XW1T, FIN, FIN, MR, FIN, 0, 1, 0, 0, 0, 0, 0, 1.0f);

  // Hb = relu(Adjb @ XW1_b + b1)  bf16 [8192][256]
  gemm_mfma<2, 0, 1, true, true><<<dim3(2, 8, NB), 256, 0, stream>>>(
      Adjb, nullptr, XW1T, b1, Hb,
      NN, 0, FH, NN, 0, 1, 1024, 0, 0, (size_t)NN * FH, 0, 1.0f);

  // G2T[(b,f)][(h,node)] = sum_c WmT[h][f][c] * Hb[b][node][c]
  gemm_mfma<2, 0, 0, false, false><<<dim3(8, 2, 16), 256, 0, stream>>>(
      WmT, nullptr, Hb, nullptr, G2T,
      FH, FH, 2048, FH, 0, 2, 0,
      (size_t)FH * FH, (size_t)NN * FH, (size_t)FH * 2048, 1024, 1.0f);

  for (int c = 0; c < nchunk; ++c) {
    // Dt[(b,f128)][e] = relu([m_in|m_out] @ G2T^T + bm) @ W2  (fused)
    egemm8<<<dim3(EC / 256, 8, 1), 512, 0, stream>>>(
        m_in_bf, m_out_bf, G2T, bm, W2T, Dt, c * EC, EC);
    // H2X += m_inT_chunk @ Dt^T  fp32 atomics, split-K (/1024 folded later)
    gemm_mfma<1, 0, 0, false, false><<<dim3(8, 8, nsplit), 256, 0, stream>>>(
        m_inT + (size_t)c * EC, nullptr, Dt, nullptr, H2X,
        32768, EC, 1024, EC, EC / nsplit, 1, 0, 0, 0, 0, 0, 1.0f);
  }

  // XW2T[f128][(b,node)] = bf16(H2X / 1024)
  k_repack2<<<dim3(32, 32), 256, 0, stream>>>(H2X, XW2T);

  // out_b = Adjb @ XW2_b + b2  fp32 [8192][128]
  gemm_mfma<3, 0, 1, true, false><<<dim3(1, 8, NB), 256, 0, stream>>>(
      Adjb, nullptr, XW2T, b2, out,
      NN, 0, FOUT, NN, 0, 1, 1024, 0, 0, (size_t)NN * FOUT, 0, 1.0f);
}

// Round 17
// 583.227 us; speedup vs baseline: 1.0551x; 1.0458x over previous
//
#include <hip/hip_runtime.h>
#include <hip/hip_bf16.h>

typedef __attribute__((ext_vector_type(8))) short bf16x8;
typedef __attribute__((ext_vector_type(4))) float f32x4;

static constexpr int NB   = 8;
static constexpr int NN   = 1024;
static constexpr int NE   = 32768;
static constexpr int FIN  = 128;
static constexpr int FH   = 256;
static constexpr int FOUT = 128;
static constexpr int MR   = NB * NN;

__device__ __forceinline__ short f2bf(float f) {
  union { __hip_bfloat16 h; short s; } u;
  u.h = __float2bfloat16(f);
  return u.s;
}

typedef const __attribute__((address_space(1))) void gas_void;
typedef __attribute__((address_space(3))) void las_void;
__device__ __forceinline__ void glds16(short* lds, const short* g) {
  __builtin_amdgcn_global_load_lds((gas_void*)g, (las_void*)lds, 16, 0, 0);
}
__device__ __forceinline__ void BAR() {
  asm volatile("" ::: "memory");
  __builtin_amdgcn_s_barrier();
  asm volatile("" ::: "memory");
}

// ---- graph preprocessing -------------------------------------------------
__global__ void k_deg(const int* __restrict__ dst, int* __restrict__ deg) {
  int e = blockIdx.x * blockDim.x + threadIdx.x;
  if (e < NE) atomicAdd(&deg[dst[e]], 1);
}
__global__ void k_adj(const int* __restrict__ src, const int* __restrict__ dst,
                      const int* __restrict__ deg, float* __restrict__ Adj) {
  int t = blockIdx.x * blockDim.x + threadIdx.x;
  if (t < NE) {
    int s = src[t], d = dst[t];
    float ds = rsqrtf((float)(deg[s] + 1));
    float dd = rsqrtf((float)(deg[d] + 1));
    atomicAdd(&Adj[d * NN + s], ds * dd);
  } else if (t < NE + NN) {
    int n = t - NE;
    float dn = rsqrtf((float)(deg[n] + 1));
    atomicAdd(&Adj[n * NN + n], dn * dn);
  }
}

// ---- layout / cast kernels ----------------------------------------------
__global__ __launch_bounds__(256) void k_cast(const float4* __restrict__ S,
                                              short* __restrict__ D) {
  size_t q = (size_t)blockIdx.x * 256 + threadIdx.x;
  float4 a = S[q];
  short4 p;
  p.x = f2bf(a.x); p.y = f2bf(a.y); p.z = f2bf(a.z); p.w = f2bf(a.w);
  *(short4*)&D[q * 4] = p;
}
__global__ __launch_bounds__(256) void k_wt(const float* __restrict__ W1,
                                            const float* __restrict__ Wm,
                                            const float* __restrict__ W2,
                                            short* __restrict__ W1T,
                                            short* __restrict__ WmT,
                                            short* __restrict__ W2T) {
  int idx = blockIdx.x * 256 + threadIdx.x;
  if (idx < 128 * 256) {
    int r = idx >> 8, c = idx & 255;
    W1T[c * 128 + r] = f2bf(W1[idx]);
  } else if (idx < 128 * 256 + 512 * 256) {
    int k = idx - 128 * 256;
    int r = k >> 8, c = k & 255;
    int h = r >> 8, kk = r & 255;
    WmT[h * 65536 + c * 256 + kk] = f2bf(Wm[k]);
  } else {
    int k = idx - 128 * 256 - 512 * 256;
    int r = k >> 7, c = k & 127;
    W2T[c * 256 + r] = f2bf(W2[k]);
  }
}
// z=0: m_in -> mi_bf (vectorized) + miT (tile transpose); z=1: m_out -> mo_bf
__global__ __launch_bounds__(256) void k_prep(const float* __restrict__ mi,
                                              const float* __restrict__ mo,
                                              short* __restrict__ mi_bf,
                                              short* __restrict__ mo_bf,
                                              short* __restrict__ miT) {
  int tid = threadIdx.x;
  int e0 = blockIdx.x * 64, n0 = blockIdx.y * 64;
  if (blockIdx.z == 1) {
    #pragma unroll
    for (int it = 0; it < 4; ++it) {
      int r = it * 16 + (tid >> 4);
      int c4 = (tid & 15) * 4;
      float4 v = *(const float4*)&mo[(size_t)(e0 + r) * 1024 + n0 + c4];
      short4 p;
      p.x = f2bf(v.x); p.y = f2bf(v.y); p.z = f2bf(v.z); p.w = f2bf(v.w);
      *(short4*)&mo_bf[(size_t)(e0 + r) * 1024 + n0 + c4] = p;
    }
    return;
  }
  __shared__ short tile[64][71];
  #pragma unroll
  for (int it = 0; it < 4; ++it) {
    int r = it * 16 + (tid >> 4);
    int c4 = (tid & 15) * 4;
    float4 v = *(const float4*)&mi[(size_t)(e0 + r) * 1024 + n0 + c4];
    short4 p;
    p.x = f2bf(v.x); p.y = f2bf(v.y); p.z = f2bf(v.z); p.w = f2bf(v.w);
    *(short4*)&mi_bf[(size_t)(e0 + r) * 1024 + n0 + c4] = p;
    tile[c4 + 0][r] = p.x;
    tile[c4 + 1][r] = p.y;
    tile[c4 + 2][r] = p.z;
    tile[c4 + 3][r] = p.w;
  }
  __syncthreads();
  int n = tid >> 2, ec = (tid & 3) * 16;
  #pragma unroll
  for (int q = 0; q < 4; ++q) {
    short4 v;
    v.x = tile[n][ec + q * 4 + 0];
    v.y = tile[n][ec + q * 4 + 1];
    v.z = tile[n][ec + q * 4 + 2];
    v.w = tile[n][ec + q * 4 + 3];
    *(short4*)&miT[(size_t)(n0 + n) * 32768 + e0 + ec + q * 4] = v;
  }
}
// atomic-path repack: XW2T[f128][(b,node)] = bf16(H2X[node][b*128+f] / 1024)
__global__ __launch_bounds__(256) void k_repack2(const float* __restrict__ H2X,
                                                 short* __restrict__ XW2T) {
  __shared__ float t[32][33];
  int n0 = blockIdx.x * 32, c0 = blockIdx.y * 32;
  int r = threadIdx.x >> 5, cc = threadIdx.x & 31;
  #pragma unroll
  for (int p = 0; p < 4; ++p)
    t[r + p * 8][cc] = H2X[(size_t)(n0 + r + p * 8) * 1024 + c0 + cc];
  __syncthreads();
  const float inv = 1.0f / 1024.0f;
  #pragma unroll
  for (int p = 0; p < 4; ++p) {
    int c = c0 + r + p * 8;
    int b = c >> 7, f = c & 127;
    XW2T[(size_t)f * 8192 + b * 1024 + n0 + cc] = f2bf(t[cc][r + p * 8] * inv);
  }
}
// plain-path: sum ns partials, /1024, transpose-store
__global__ __launch_bounds__(256) void k_repack3(const float* __restrict__ Part,
                                                 short* __restrict__ XW2T, int ns) {
  __shared__ float t[32][33];
  int n0 = blockIdx.x * 32, c0 = blockIdx.y * 32;
  int r = threadIdx.x >> 5, cc = threadIdx.x & 31;
  #pragma unroll
  for (int p = 0; p < 4; ++p) {
    size_t base = (size_t)(n0 + r + p * 8) * 1024 + c0 + cc;
    float s = 0.0f;
    for (int z = 0; z < ns; ++z) s += Part[(size_t)z * 1024 * 1024 + base];
    t[r + p * 8][cc] = s;
  }
  __syncthreads();
  const float inv = 1.0f / 1024.0f;
  #pragma unroll
  for (int p = 0; p < 4; ++p) {
    int c = c0 + r + p * 8;
    int b = c >> 7, f = c & 127;
    XW2T[(size_t)f * 8192 + b * 1024 + n0 + cc] = f2bf(t[cc][r + p * 8] * inv);
  }
}

// ---- proven 128x128 bf16 MFMA GEMM: C = A[M,K] @ BT[N,K]^T ---------------
// EPI 4: fp32 plain per-z partial store Cf[z*szC + row*ldc + col]
//        (= if scale==0, += if scale!=0). No atomics; z = split-K.
template <int EPI, int ASRC, int BSEL, bool BIAS, bool RELU>
__launch_bounds__(256)
__global__ void gemm_mfma(const short* __restrict__ Ab, const float* __restrict__ Af,
                          const short* __restrict__ BT, const float* __restrict__ bias,
                          void* __restrict__ Cv,
                          int lda, int ldb, int ldc, int K, int kSplit, int nz2,
                          int zcolB, size_t szA, size_t szB, size_t szC, size_t szC2,
                          float scale) {
  __shared__ __align__(16) short As[128 * 64];
  __shared__ __align__(16) short Bs[128 * 64];

  const int tid = threadIdx.x;
  const int lane = tid & 63, wid = tid >> 6;
  const int wr = wid >> 1, wc = wid & 1;
  const int fr = lane & 15, fq = lane >> 4;
  const int m0 = blockIdx.y * 128, n0 = blockIdx.x * 128;

  int zA = 0, zB = 0, k0 = 0, k1 = K;
  if constexpr (EPI == 1 || EPI == 4) {
    k0 = blockIdx.z * kSplit; k1 = k0 + kSplit;
  } else {
    zA = (int)blockIdx.z % nz2; zB = (int)blockIdx.z / nz2;
  }
  if constexpr (ASRC == 0) Ab += (size_t)zA * szA;
  else                     Af += (size_t)zA * szA;
  BT += (size_t)zB * szB;
  const int colB = zB * zcolB;

  const int rq = lane >> 3;
  const int ks = (lane & 7) ^ rq;

  f32x4 acc[4][4] = {};

  for (int kt = k0; kt < k1; kt += 64) {
    if constexpr (ASRC == 2) {
      #pragma unroll
      for (int p = 0; p < 4; ++p) {
        int i = p * 256 + tid, row = i >> 3, g = i & 7;
        const float* ap = Af + (size_t)(m0 + row) * lda + kt + g * 8;
        bf16x8 v;
        #pragma unroll
        for (int e = 0; e < 8; ++e) v[e] = f2bf(ap[e]);
        *(bf16x8*)&As[row * 64 + ((g ^ (row & 7)) * 8)] = v;
      }
    } else {
      #pragma unroll
      for (int c = 0; c < 4; ++c) {
        int row = wid * 32 + c * 8 + rq;
        glds16(&As[(wid * 256 + c * 64) * 8],
               Ab + (size_t)(m0 + row) * lda + kt + ks * 8);
      }
    }
    {
      const short* Bsrc;
      int ldbe;
      if constexpr (BSEL == 1) { Bsrc = BT + colB; ldbe = 8192; }
      else                     { Bsrc = BT;        ldbe = ldb;  }
      #pragma unroll
      for (int c = 0; c < 4; ++c) {
        int row = wid * 32 + c * 8 + rq;
        glds16(&Bs[(wid * 256 + c * 64) * 8],
               Bsrc + (size_t)(n0 + row) * ldbe + kt + ks * 8);
      }
    }
    __syncthreads();
    bf16x8 afv[4][2], bfv[4][2];
    #pragma unroll
    for (int i = 0; i < 4; ++i) {
      int row = wr * 64 + i * 16 + fr;
      #pragma unroll
      for (int kh = 0; kh < 2; ++kh)
        afv[i][kh] = *(const bf16x8*)&As[row * 64 + (((kh * 4 + fq) ^ (fr & 7)) * 8)];
    }
    #pragma unroll
    for (int j = 0; j < 4; ++j) {
      int row = wc * 64 + j * 16 + fr;
      #pragma unroll
      for (int kh = 0; kh < 2; ++kh)
        bfv[j][kh] = *(const bf16x8*)&Bs[row * 64 + (((kh * 4 + fq) ^ (fr & 7)) * 8)];
    }
    #pragma unroll
    for (int i = 0; i < 4; ++i)
      #pragma unroll
      for (int j = 0; j < 4; ++j) {
        acc[i][j] = __builtin_amdgcn_mfma_f32_16x16x32_bf16(afv[i][0], bfv[j][0], acc[i][j], 0, 0, 0);
        acc[i][j] = __builtin_amdgcn_mfma_f32_16x16x32_bf16(afv[i][1], bfv[j][1], acc[i][j], 0, 0, 0);
      }
    __syncthreads();
  }

  const size_t cOff = (size_t)zB * szC + (size_t)zA * szC2;
  #pragma unroll
  for (int i = 0; i < 4; ++i) {
    int rowb = m0 + wr * 64 + i * 16 + fq * 4;
    #pragma unroll
    for (int j = 0; j < 4; ++j) {
      int col = n0 + wc * 64 + j * 16 + fr;
      float bv = 0.0f;
      if constexpr (BIAS) bv = bias[col];
      float v0 = acc[i][j][0] + bv, v1 = acc[i][j][1] + bv;
      float v2 = acc[i][j][2] + bv, v3 = acc[i][j][3] + bv;
      if constexpr (RELU) {
        v0 = fmaxf(v0, 0.0f); v1 = fmaxf(v1, 0.0f);
        v2 = fmaxf(v2, 0.0f); v3 = fmaxf(v3, 0.0f);
      }
      if constexpr (EPI == 0) {
        short* Ct = (short*)Cv + cOff;
        short4 pk;
        pk.x = f2bf(v0); pk.y = f2bf(v1); pk.z = f2bf(v2); pk.w = f2bf(v3);
        *(short4*)(Ct + (size_t)col * ldc + rowb) = pk;
      } else if constexpr (EPI == 1) {
        float* Cf = (float*)Cv;
        atomicAdd(&Cf[(size_t)(rowb + 0) * ldc + col], acc[i][j][0] * scale);
        atomicAdd(&Cf[(size_t)(rowb + 1) * ldc + col], acc[i][j][1] * scale);
        atomicAdd(&Cf[(size_t)(rowb + 2) * ldc + col], acc[i][j][2] * scale);
        atomicAdd(&Cf[(size_t)(rowb + 3) * ldc + col], acc[i][j][3] * scale);
      } else if constexpr (EPI == 2) {
        short* Cn = (short*)Cv + cOff;
        Cn[(size_t)(rowb + 0) * ldc + col] = f2bf(v0);
        Cn[(size_t)(rowb + 1) * ldc + col] = f2bf(v1);
        Cn[(size_t)(rowb + 2) * ldc + col] = f2bf(v2);
        Cn[(size_t)(rowb + 3) * ldc + col] = f2bf(v3);
      } else if constexpr (EPI == 4) {
        float* Cf = (float*)Cv + (size_t)blockIdx.z * szC;
        #pragma unroll
        for (int r = 0; r < 4; ++r) {
          float* p = &Cf[(size_t)(rowb + r) * ldc + col];
          float old = (scale != 0.0f) ? *p : 0.0f;
          *p = old + acc[i][j][r];
        }
      } else {
        float* Cf = (float*)Cv + cOff;
        Cf[(size_t)(rowb + 0) * ldc + col] = v0;
        Cf[(size_t)(rowb + 1) * ldc + col] = v1;
        Cf[(size_t)(rowb + 2) * ldc + col] = v2;
        Cf[(size_t)(rowb + 3) * ldc + col] = v3;
      }
    }
  }
}

// ---- 8-phase 256x256 edge GEMM + FUSED D epilogue (R16, unchanged) -------
__launch_bounds__(512, 2)
__global__ void egemm8(const short* __restrict__ Ain, const short* __restrict__ Aout,
                       const short* __restrict__ G2T, const float* __restrict__ bm,
                       const short* __restrict__ W2T, short* __restrict__ Dt,
                       int e0, int EC) {
  __shared__ __align__(16) short SMEM[65536];    // 128 KB
  short* As0 = SMEM;            // [2][16384]
  short* Bs0 = SMEM + 32768;    // [2][16384]

  const int tid = threadIdx.x;
  const int lane = tid & 63, wid = tid >> 6;
  const int wm = wid >> 2, wn = wid & 3;
  const int fr = lane & 15, fq = lane >> 4;
  const int m0 = blockIdx.x * 256;       // e-row tile
  const int n0 = blockIdx.y * 256;       // column band = batch by * 256
  const size_t arow0 = (size_t)(e0 + m0) * 1024;

  const int rl = tid >> 3;
  const int ce = ((tid & 7) ^ (rl & 7)) << 3;
  const int ldst = wid << 9;

  f32x4 acc[8][4] = {};

  auto stageA = [&](int buf, int kt, int iss) {
    const short* s = (kt < 1024 ? Ain : Aout) + arow0
                   + (size_t)(iss * 64 + rl) * 1024 + (kt & 1023) + ce;
    glds16(&As0[buf * 16384 + iss * 4096 + ldst], s);
  };
  auto stageB = [&](int buf, int kt, int iss) {
    const short* s = G2T + (size_t)(n0 + iss * 64 + rl) * 2048 + kt + ce;
    glds16(&Bs0[buf * 16384 + iss * 4096 + ldst], s);
  };

#define EG_PHASE(QM, QN, STAGES, WAITOP)                                          \
  {                                                                               \
    bf16x8 af[4][2], bv[2][2];                                                    \
    _Pragma("unroll")                                                             \
    for (int i = 0; i < 4; ++i) {                                                 \
      int r = wm * 128 + ((QM) * 4 + i) * 16 + fr;                                \
      _Pragma("unroll")                                                           \
      for (int s = 0; s < 2; ++s)                                                 \
        af[i][s] = *(const bf16x8*)&As0[buf * 16384 + r * 64 + (((s * 4 + fq) ^ (r & 7)) << 3)]; \
    }                                                                             \
    _Pragma("unroll")                                                             \
    for (int j = 0; j < 2; ++j) {                                                 \
      int rb = wn * 64 + ((QN) * 2 + j) * 16 + fr;                                \
      _Pragma("unroll")                                                           \
      for (int s = 0; s < 2; ++s)                                                 \
        bv[j][s] = *(const bf16x8*)&Bs0[buf * 16384 + rb * 64 + (((s * 4 + fq) ^ (rb & 7)) << 3)]; \
    }                                                                             \
    STAGES                                                                        \
    WAITOP                                                                        \
    BAR();                                                                        \
    asm volatile("s_waitcnt lgkmcnt(0)" ::: "memory");                            \
    __builtin_amdgcn_s_setprio(1);                                                \
    _Pragma("unroll")                                                             \
    for (int i = 0; i < 4; ++i)                                                   \
      _Pragma("unroll")                                                           \
      for (int j = 0; j < 2; ++j) {                                               \
        acc[(QM) * 4 + i][(QN) * 2 + j] = __builtin_amdgcn_mfma_f32_16x16x32_bf16(\
            af[i][0], bv[j][0], acc[(QM) * 4 + i][(QN) * 2 + j], 0, 0, 0);        \
        acc[(QM) * 4 + i][(QN) * 2 + j] = __builtin_amdgcn_mfma_f32_16x16x32_bf16(\
            af[i][1], bv[j][1], acc[(QM) * 4 + i][(QN) * 2 + j], 0, 0, 0);        \
      }                                                                           \
    __builtin_amdgcn_s_setprio(0);                                                \
    BAR();                                                                        \
  }

  #pragma unroll
  for (int i = 0; i < 4; ++i) stageA(0, 0, i);
  #pragma unroll
  for (int i = 0; i < 4; ++i) stageB(0, 0, i);
  asm volatile("s_waitcnt vmcnt(0)" ::: "memory");
  BAR();

  constexpr int NT = 2048 / 64;
  for (int t = 0; t < NT; ++t) {
    const int buf = t & 1, nb = buf ^ 1, ktn = (t + 1) * 64;
    const bool pre = (t + 1 < NT);
    EG_PHASE(0, 0, { if (pre) { stageA(nb, ktn, 0); stageA(nb, ktn, 2); } }, ;)
    EG_PHASE(0, 1, { if (pre) { stageB(nb, ktn, 0); stageB(nb, ktn, 1); } },
             asm volatile("s_waitcnt vmcnt(4)" ::: "memory");)
    EG_PHASE(1, 0, { if (pre) { stageB(nb, ktn, 2); stageB(nb, ktn, 3); } }, ;)
    EG_PHASE(1, 1, { if (pre) { stageA(nb, ktn, 1); stageA(nb, ktn, 3); } },
             asm volatile("s_waitcnt vmcnt(2)" ::: "memory");)
  }
#undef EG_PHASE

  // ---- fused D epilogue ----------------------------------------------
  #pragma unroll
  for (int i = 0; i < 8; ++i) {
    int eb = wm * 128 + i * 16 + fq * 4;
    #pragma unroll
    for (int j = 0; j < 4; ++j) {
      int f = wn * 64 + j * 16 + fr;
      float bb = bm[f];
      #pragma unroll
      for (int r = 0; r < 4; ++r) {
        int er = eb + r;
        SMEM[er * 256 + ((((f >> 3) ^ (er & 7)) << 3) | (f & 7))] =
            f2bf(fmaxf(acc[i][j][r] + bb, 0.0f));
      }
    }
  }
  asm volatile("s_waitcnt lgkmcnt(0)" ::: "memory");
  BAR();
  bf16x8 w2f[2][8];
  #pragma unroll
  for (int jj = 0; jj < 2; ++jj) {
    int row = wn * 32 + jj * 16 + fr;
    #pragma unroll
    for (int kk = 0; kk < 8; ++kk)
      w2f[jj][kk] = *(const bf16x8*)(W2T + (size_t)row * 256 + kk * 32 + fq * 8);
  }
  f32x4 dacc[8][2] = {};
  #pragma unroll
  for (int kk = 0; kk < 8; ++kk) {
    #pragma unroll
    for (int ii = 0; ii < 8; ++ii) {
      int er = wm * 128 + ii * 16 + fr;
      bf16x8 a = *(const bf16x8*)&SMEM[er * 256 + (((kk * 4 + fq) ^ (er & 7)) << 3)];
      dacc[ii][0] = __builtin_amdgcn_mfma_f32_16x16x32_bf16(a, w2f[0][kk], dacc[ii][0], 0, 0, 0);
      dacc[ii][1] = __builtin_amdgcn_mfma_f32_16x16x32_bf16(a, w2f[1][kk], dacc[ii][1], 0, 0, 0);
    }
  }
  const int bcol = blockIdx.y;
  #pragma unroll
  for (int ii = 0; ii < 8; ++ii) {
    int e = m0 + wm * 128 + ii * 16 + fq * 4;
    #pragma unroll
    for (int jj = 0; jj < 2; ++jj) {
      int frow = bcol * 128 + wn * 32 + jj * 16 + fr;
      short4 pk;
      pk.x = f2bf(dacc[ii][jj][0]);
      pk.y = f2bf(dacc[ii][jj][1]);
      pk.z = f2bf(dacc[ii][jj][2]);
      pk.w = f2bf(dacc[ii][jj][3]);
      *(short4*)&Dt[(size_t)frow * EC + e] = pk;
    }
  }
}

// ---- launch --------------------------------------------------------------
extern "C" void kernel_launch(void* const* d_in, const int* in_sizes, int n_in,
                              void* d_out, int out_size, void* d_ws, size_t ws_size,
                              hipStream_t stream) {
  const float* x     = (const float*)d_in[0];
  const int*   ei    = (const int*)d_in[1];
  const float* m_in  = (const float*)d_in[2];
  const float* m_out = (const float*)d_in[3];
  const float* W1    = (const float*)d_in[4];
  const float* b1    = (const float*)d_in[5];
  const float* Wm    = (const float*)d_in[6];
  const float* bm    = (const float*)d_in[7];
  const float* W2    = (const float*)d_in[8];
  const float* b2    = (const float*)d_in[9];
  float* out = (float*)d_out;
  const int* src = ei;
  const int* dst = ei + NE;

  char* w = (char*)d_ws;
  size_t used = 0;
  auto alloc = [&](size_t bytes) {
    char* p = w; size_t r = (bytes + 255) & ~(size_t)255;
    w += r; used += r; return p;
  };
  int*   deg    = (int*)  alloc((size_t)NN * 4);
  short* Adjb   = (short*)alloc((size_t)NN * NN * 2);        // 2 MB
  short* W1T    = (short*)alloc((size_t)FH * FIN * 2);
  short* WmT    = (short*)alloc((size_t)2 * FH * FH * 2);
  short* W2T    = (short*)alloc((size_t)FOUT * FH * 2);
  short* G2T    = (short*)alloc((size_t)2048 * 2048 * 2);    // 8 MB [(b,f)][(h,node)]
  float* H2X    = (float*)alloc((size_t)NN * 1024 * 4);      // 4 MB (atomic fallback)
  short* m_in_bf  = (short*)alloc((size_t)NE * NN * 2);      // 64 MB
  short* m_out_bf = (short*)alloc((size_t)NE * NN * 2);      // 64 MB
  short* m_inT    = (short*)alloc((size_t)NN * NE * 2);      // 64 MB [1024][32768]

  // union region U: {Adj,XW1T,Hb} -> {Dt} -> {XW2T}
  int EC = 4096;
  for (int ec : {32768, 16384, 8192}) {
    size_t need = (size_t)ec * 2048;   // Dt = ec*1024*2 bytes
    if (need < (12u << 20)) need = 12u << 20;
    if (used + need + (1u << 20) <= ws_size) { EC = ec; break; }
  }
  size_t ubytes = (size_t)EC * 2048;
  if (ubytes < (12u << 20)) ubytes = 12u << 20;
  char* U = alloc(ubytes);
  float* Adj  = (float*)U;                        // 4 MB   (early)
  short* XW1T = (short*)(U + (4u << 20));         // 4 MB   (early) [256][8192]
  short* Hb   = (short*)(U + (8u << 20));         // 4 MB   (early) [8192][256]
  short* Dt   = (short*)U;                        // EC*1024*2 (mid) [1024][EC]
  short* XW2T = (short*)U;                        // 2 MB   (late)  [128][8192]

  const int nchunk = NE / EC;
  const int nsplit = 8;
  // plain-store partials (no atomics) if workspace allows
  bool plain = (used + (size_t)nsplit * 4 * (1u << 20) + (1u << 20) <= ws_size);
  float* Part = plain ? (float*)alloc((size_t)nsplit * 4 * (1u << 20)) : nullptr;

  hipMemsetAsync(deg, 0, (size_t)NN * 4, stream);
  hipMemsetAsync(Adj, 0, (size_t)NN * NN * 4, stream);
  if (!plain) hipMemsetAsync(H2X, 0, (size_t)NN * 1024 * 4, stream);

  k_deg<<<(NE + 255) / 256, 256, 0, stream>>>(dst, deg);
  k_adj<<<(NE + NN + 255) / 256, 256, 0, stream>>>(src, dst, deg, Adj);
  k_cast<<<NN * NN / 4 / 256, 256, 0, stream>>>((const float4*)Adj, Adjb);

  k_wt<<<(128 * 256 + 512 * 256 + 256 * 128) / 256, 256, 0, stream>>>(
      W1, Wm, W2, W1T, WmT, W2T);
  k_prep<<<dim3(NE / 64, NN / 64, 2), 256, 0, stream>>>(
      m_in, m_out, m_in_bf, m_out_bf, m_inT);

  // XW1T = (x @ W1)^T  bf16 [256][8192]
  gemm_mfma<0, 2, 0, false, false><<<dim3(2, 64, 1), 256, 0, stream>>>(
      nullptr, x, W1T, nullptr, XW1T, FIN, FIN, MR, FIN, 0, 1, 0, 0, 0, 0, 0, 1.0f);

  // Hb = relu(Adjb @ XW1_b + b1)  bf16 [8192][256]
  gemm_mfma<2, 0, 1, true, true><<<dim3(2, 8, NB), 256, 0, stream>>>(
      Adjb, nullptr, XW1T, b1, Hb,
      NN, 0, FH, NN, 0, 1, 1024, 0, 0, (size_t)NN * FH, 0, 1.0f);

  // G2T[(b,f)][(h,node)] = sum_c WmT[h][f][c] * Hb[b][node][c]
  gemm_mfma<2, 0, 0, false, false><<<dim3(8, 2, 16), 256, 0, stream>>>(
      WmT, nullptr, Hb, nullptr, G2T,
      FH, FH, 2048, FH, 0, 2, 0,
      (size_t)FH * FH, (size_t)NN * FH, (size_t)FH * 2048, 1024, 1.0f);

  for (int c = 0; c < nchunk; ++c) {
    // Dt[(b,f128)][e] = relu([m_in|m_out] @ G2T^T + bm) @ W2  (fused)
    egemm8<<<dim3(EC / 256, 8, 1), 512, 0, stream>>>(
        m_in_bf, m_out_bf, G2T, bm, W2T, Dt, c * EC, EC);
    if (plain) {
      // Part[z] (+)= m_inT_chunk @ Dt^T  (plain stores, race-free per (tile,z))
      gemm_mfma<4, 0, 0, false, false><<<dim3(8, 8, nsplit), 256, 0, stream>>>(
          m_inT + (size_t)c * EC, nullptr, Dt, nullptr, Part,
          32768, EC, 1024, EC, EC / nsplit, 1, 0, 0, 0,
          (size_t)1024 * 1024, 0, c == 0 ? 0.0f : 1.0f);
    } else {
      // H2X += m_inT_chunk @ Dt^T  fp32 atomics
      gemm_mfma<1, 0, 0, false, false><<<dim3(8, 8, nsplit), 256, 0, stream>>>(
          m_inT + (size_t)c * EC, nullptr, Dt, nullptr, H2X,
          32768, EC, 1024, EC, EC / nsplit, 1, 0, 0, 0, 0, 0, 1.0f);
    }
  }

  // XW2T[f128][(b,node)] = bf16(sum partials / 1024)
  if (plain) k_repack3<<<dim3(32, 32), 256, 0, stream>>>(Part, XW2T, nsplit);
  else       k_repack2<<<dim3(32, 32), 256, 0, stream>>>(H2X, XW2T);

  // out_b = Adjb @ XW2_b + b2  fp32 [8192][128]
  gemm_mfma<3, 0, 1, true, false><<<dim3(1, 8, NB), 256, 0, stream>>>(
      Adjb, nullptr, XW2T, b2, out,
      NN, 0, FOUT, NN, 0, 1, 1024, 0, 0, (size_t)NN * FOUT, 0, 1.0f);
}

// Round 18
// 560.785 us; speedup vs baseline: 1.0973x; 1.0400x over previous
//
#include <hip/hip_runtime.h>
#include <hip/hip_bf16.h>

typedef __attribute__((ext_vector_type(8))) short bf16x8;
typedef __attribute__((ext_vector_type(4))) float f32x4;

static constexpr int NB   = 8;
static constexpr int NN   = 1024;
static constexpr int NE   = 32768;
static constexpr int FIN  = 128;
static constexpr int FH   = 256;
static constexpr int FOUT = 128;
static constexpr int MR   = NB * NN;

__device__ __forceinline__ short f2bf(float f) {
  union { __hip_bfloat16 h; short s; } u;
  u.h = __float2bfloat16(f);
  return u.s;
}

typedef const __attribute__((address_space(1))) void gas_void;
typedef __attribute__((address_space(3))) void las_void;
__device__ __forceinline__ void glds16(short* lds, const short* g) {
  __builtin_amdgcn_global_load_lds((gas_void*)g, (las_void*)lds, 16, 0, 0);
}
__device__ __forceinline__ void BAR() {
  asm volatile("" ::: "memory");
  __builtin_amdgcn_s_barrier();
  asm volatile("" ::: "memory");
}

// ---- graph preprocessing -------------------------------------------------
__global__ void k_deg(const int* __restrict__ dst, int* __restrict__ deg) {
  int e = blockIdx.x * blockDim.x + threadIdx.x;
  if (e < NE) atomicAdd(&deg[dst[e]], 1);
}
__global__ void k_adj(const int* __restrict__ src, const int* __restrict__ dst,
                      const int* __restrict__ deg, float* __restrict__ Adj) {
  int t = blockIdx.x * blockDim.x + threadIdx.x;
  if (t < NE) {
    int s = src[t], d = dst[t];
    float ds = rsqrtf((float)(deg[s] + 1));
    float dd = rsqrtf((float)(deg[d] + 1));
    atomicAdd(&Adj[d * NN + s], ds * dd);
  } else if (t < NE + NN) {
    int n = t - NE;
    float dn = rsqrtf((float)(deg[n] + 1));
    atomicAdd(&Adj[n * NN + n], dn * dn);
  }
}

// ---- layout / cast kernels ----------------------------------------------
__global__ __launch_bounds__(256) void k_cast(const float4* __restrict__ S,
                                              short* __restrict__ D) {
  size_t q = (size_t)blockIdx.x * 256 + threadIdx.x;
  float4 a = S[q];
  short4 p;
  p.x = f2bf(a.x); p.y = f2bf(a.y); p.z = f2bf(a.z); p.w = f2bf(a.w);
  *(short4*)&D[q * 4] = p;
}
__global__ __launch_bounds__(256) void k_wt(const float* __restrict__ W1,
                                            const float* __restrict__ Wm,
                                            const float* __restrict__ W2,
                                            short* __restrict__ W1T,
                                            short* __restrict__ WmT,
                                            short* __restrict__ W2T) {
  int idx = blockIdx.x * 256 + threadIdx.x;
  if (idx < 128 * 256) {
    int r = idx >> 8, c = idx & 255;
    W1T[c * 128 + r] = f2bf(W1[idx]);
  } else if (idx < 128 * 256 + 512 * 256) {
    int k = idx - 128 * 256;
    int r = k >> 8, c = k & 255;
    int h = r >> 8, kk = r & 255;
    WmT[h * 65536 + c * 256 + kk] = f2bf(Wm[k]);
  } else {
    int k = idx - 128 * 256 - 512 * 256;
    int r = k >> 7, c = k & 127;
    W2T[c * 256 + r] = f2bf(W2[k]);
  }
}
// z=0: m_in -> mi_bf (vectorized) + miT (tile transpose); z=1: m_out -> mo_bf
__global__ __launch_bounds__(256) void k_prep(const float* __restrict__ mi,
                                              const float* __restrict__ mo,
                                              short* __restrict__ mi_bf,
                                              short* __restrict__ mo_bf,
                                              short* __restrict__ miT) {
  int tid = threadIdx.x;
  int e0 = blockIdx.x * 64, n0 = blockIdx.y * 64;
  if (blockIdx.z == 1) {
    #pragma unroll
    for (int it = 0; it < 4; ++it) {
      int r = it * 16 + (tid >> 4);
      int c4 = (tid & 15) * 4;
      float4 v = *(const float4*)&mo[(size_t)(e0 + r) * 1024 + n0 + c4];
      short4 p;
      p.x = f2bf(v.x); p.y = f2bf(v.y); p.z = f2bf(v.z); p.w = f2bf(v.w);
      *(short4*)&mo_bf[(size_t)(e0 + r) * 1024 + n0 + c4] = p;
    }
    return;
  }
  __shared__ short tile[64][71];
  #pragma unroll
  for (int it = 0; it < 4; ++it) {
    int r = it * 16 + (tid >> 4);
    int c4 = (tid & 15) * 4;
    float4 v = *(const float4*)&mi[(size_t)(e0 + r) * 1024 + n0 + c4];
    short4 p;
    p.x = f2bf(v.x); p.y = f2bf(v.y); p.z = f2bf(v.z); p.w = f2bf(v.w);
    *(short4*)&mi_bf[(size_t)(e0 + r) * 1024 + n0 + c4] = p;
    tile[c4 + 0][r] = p.x;
    tile[c4 + 1][r] = p.y;
    tile[c4 + 2][r] = p.z;
    tile[c4 + 3][r] = p.w;
  }
  __syncthreads();
  int n = tid >> 2, ec = (tid & 3) * 16;
  #pragma unroll
  for (int q = 0; q < 4; ++q) {
    short4 v;
    v.x = tile[n][ec + q * 4 + 0];
    v.y = tile[n][ec + q * 4 + 1];
    v.z = tile[n][ec + q * 4 + 2];
    v.w = tile[n][ec + q * 4 + 3];
    *(short4*)&miT[(size_t)(n0 + n) * 32768 + e0 + ec + q * 4] = v;
  }
}
// atomic-path repack: XW2T[f128][(b,node)] = bf16(H2X[node][b*128+f] / 1024)
__global__ __launch_bounds__(256) void k_repack2(const float* __restrict__ H2X,
                                                 short* __restrict__ XW2T) {
  __shared__ float t[32][33];
  int n0 = blockIdx.x * 32, c0 = blockIdx.y * 32;
  int r = threadIdx.x >> 5, cc = threadIdx.x & 31;
  #pragma unroll
  for (int p = 0; p < 4; ++p)
    t[r + p * 8][cc] = H2X[(size_t)(n0 + r + p * 8) * 1024 + c0 + cc];
  __syncthreads();
  const float inv = 1.0f / 1024.0f;
  #pragma unroll
  for (int p = 0; p < 4; ++p) {
    int c = c0 + r + p * 8;
    int b = c >> 7, f = c & 127;
    XW2T[(size_t)f * 8192 + b * 1024 + n0 + cc] = f2bf(t[cc][r + p * 8] * inv);
  }
}
// plain-path: sum ns partials, /1024, transpose-store
__global__ __launch_bounds__(256) void k_repack3(const float* __restrict__ Part,
                                                 short* __restrict__ XW2T, int ns) {
  __shared__ float t[32][33];
  int n0 = blockIdx.x * 32, c0 = blockIdx.y * 32;
  int r = threadIdx.x >> 5, cc = threadIdx.x & 31;
  #pragma unroll
  for (int p = 0; p < 4; ++p) {
    size_t base = (size_t)(n0 + r + p * 8) * 1024 + c0 + cc;
    float s = 0.0f;
    for (int z = 0; z < ns; ++z) s += Part[(size_t)z * 1024 * 1024 + base];
    t[r + p * 8][cc] = s;
  }
  __syncthreads();
  const float inv = 1.0f / 1024.0f;
  #pragma unroll
  for (int p = 0; p < 4; ++p) {
    int c = c0 + r + p * 8;
    int b = c >> 7, f = c & 127;
    XW2T[(size_t)f * 8192 + b * 1024 + n0 + cc] = f2bf(t[cc][r + p * 8] * inv);
  }
}

// ---- proven 128x128 bf16 MFMA GEMM: C = A[M,K] @ BT[N,K]^T ---------------
template <int EPI, int ASRC, int BSEL, bool BIAS, bool RELU>
__launch_bounds__(256)
__global__ void gemm_mfma(const short* __restrict__ Ab, const float* __restrict__ Af,
                          const short* __restrict__ BT, const float* __restrict__ bias,
                          void* __restrict__ Cv,
                          int lda, int ldb, int ldc, int K, int kSplit, int nz2,
                          int zcolB, size_t szA, size_t szB, size_t szC, size_t szC2,
                          float scale) {
  __shared__ __align__(16) short As[128 * 64];
  __shared__ __align__(16) short Bs[128 * 64];

  const int tid = threadIdx.x;
  const int lane = tid & 63, wid = tid >> 6;
  const int wr = wid >> 1, wc = wid & 1;
  const int fr = lane & 15, fq = lane >> 4;
  const int m0 = blockIdx.y * 128, n0 = blockIdx.x * 128;

  int zA = 0, zB = 0, k0 = 0, k1 = K;
  if constexpr (EPI == 1 || EPI == 4) {
    k0 = blockIdx.z * kSplit; k1 = k0 + kSplit;
  } else {
    zA = (int)blockIdx.z % nz2; zB = (int)blockIdx.z / nz2;
  }
  if constexpr (ASRC == 0) Ab += (size_t)zA * szA;
  else                     Af += (size_t)zA * szA;
  BT += (size_t)zB * szB;
  const int colB = zB * zcolB;

  const int rq = lane >> 3;
  const int ks = (lane & 7) ^ rq;

  f32x4 acc[4][4] = {};

  for (int kt = k0; kt < k1; kt += 64) {
    if constexpr (ASRC == 2) {
      #pragma unroll
      for (int p = 0; p < 4; ++p) {
        int i = p * 256 + tid, row = i >> 3, g = i & 7;
        const float* ap = Af + (size_t)(m0 + row) * lda + kt + g * 8;
        bf16x8 v;
        #pragma unroll
        for (int e = 0; e < 8; ++e) v[e] = f2bf(ap[e]);
        *(bf16x8*)&As[row * 64 + ((g ^ (row & 7)) * 8)] = v;
      }
    } else {
      #pragma unroll
      for (int c = 0; c < 4; ++c) {
        int row = wid * 32 + c * 8 + rq;
        glds16(&As[(wid * 256 + c * 64) * 8],
               Ab + (size_t)(m0 + row) * lda + kt + ks * 8);
      }
    }
    {
      const short* Bsrc;
      int ldbe;
      if constexpr (BSEL == 1) { Bsrc = BT + colB; ldbe = 8192; }
      else                     { Bsrc = BT;        ldbe = ldb;  }
      #pragma unroll
      for (int c = 0; c < 4; ++c) {
        int row = wid * 32 + c * 8 + rq;
        glds16(&Bs[(wid * 256 + c * 64) * 8],
               Bsrc + (size_t)(n0 + row) * ldbe + kt + ks * 8);
      }
    }
    __syncthreads();
    bf16x8 afv[4][2], bfv[4][2];
    #pragma unroll
    for (int i = 0; i < 4; ++i) {
      int row = wr * 64 + i * 16 + fr;
      #pragma unroll
      for (int kh = 0; kh < 2; ++kh)
        afv[i][kh] = *(const bf16x8*)&As[row * 64 + (((kh * 4 + fq) ^ (fr & 7)) * 8)];
    }
    #pragma unroll
    for (int j = 0; j < 4; ++j) {
      int row = wc * 64 + j * 16 + fr;
      #pragma unroll
      for (int kh = 0; kh < 2; ++kh)
        bfv[j][kh] = *(const bf16x8*)&Bs[row * 64 + (((kh * 4 + fq) ^ (fr & 7)) * 8)];
    }
    #pragma unroll
    for (int i = 0; i < 4; ++i)
      #pragma unroll
      for (int j = 0; j < 4; ++j) {
        acc[i][j] = __builtin_amdgcn_mfma_f32_16x16x32_bf16(afv[i][0], bfv[j][0], acc[i][j], 0, 0, 0);
        acc[i][j] = __builtin_amdgcn_mfma_f32_16x16x32_bf16(afv[i][1], bfv[j][1], acc[i][j], 0, 0, 0);
      }
    __syncthreads();
  }

  const size_t cOff = (size_t)zB * szC + (size_t)zA * szC2;
  #pragma unroll
  for (int i = 0; i < 4; ++i) {
    int rowb = m0 + wr * 64 + i * 16 + fq * 4;
    #pragma unroll
    for (int j = 0; j < 4; ++j) {
      int col = n0 + wc * 64 + j * 16 + fr;
      float bv = 0.0f;
      if constexpr (BIAS) bv = bias[col];
      float v0 = acc[i][j][0] + bv, v1 = acc[i][j][1] + bv;
      float v2 = acc[i][j][2] + bv, v3 = acc[i][j][3] + bv;
      if constexpr (RELU) {
        v0 = fmaxf(v0, 0.0f); v1 = fmaxf(v1, 0.0f);
        v2 = fmaxf(v2, 0.0f); v3 = fmaxf(v3, 0.0f);
      }
      if constexpr (EPI == 0) {
        short* Ct = (short*)Cv + cOff;
        short4 pk;
        pk.x = f2bf(v0); pk.y = f2bf(v1); pk.z = f2bf(v2); pk.w = f2bf(v3);
        *(short4*)(Ct + (size_t)col * ldc + rowb) = pk;
      } else if constexpr (EPI == 1) {
        float* Cf = (float*)Cv;
        atomicAdd(&Cf[(size_t)(rowb + 0) * ldc + col], acc[i][j][0] * scale);
        atomicAdd(&Cf[(size_t)(rowb + 1) * ldc + col], acc[i][j][1] * scale);
        atomicAdd(&Cf[(size_t)(rowb + 2) * ldc + col], acc[i][j][2] * scale);
        atomicAdd(&Cf[(size_t)(rowb + 3) * ldc + col], acc[i][j][3] * scale);
      } else if constexpr (EPI == 2) {
        short* Cn = (short*)Cv + cOff;
        Cn[(size_t)(rowb + 0) * ldc + col] = f2bf(v0);
        Cn[(size_t)(rowb + 1) * ldc + col] = f2bf(v1);
        Cn[(size_t)(rowb + 2) * ldc + col] = f2bf(v2);
        Cn[(size_t)(rowb + 3) * ldc + col] = f2bf(v3);
      } else if constexpr (EPI == 4) {
        float* Cf = (float*)Cv + (size_t)blockIdx.z * szC;
        #pragma unroll
        for (int r = 0; r < 4; ++r) {
          float* p = &Cf[(size_t)(rowb + r) * ldc + col];
          float old = (scale != 0.0f) ? *p : 0.0f;
          *p = old + acc[i][j][r];
        }
      } else {
        float* Cf = (float*)Cv + cOff;
        Cf[(size_t)(rowb + 0) * ldc + col] = v0;
        Cf[(size_t)(rowb + 1) * ldc + col] = v1;
        Cf[(size_t)(rowb + 2) * ldc + col] = v2;
        Cf[(size_t)(rowb + 3) * ldc + col] = v3;
      }
    }
  }
}

// ---- 8-phase 256x256 edge GEMM + FUSED D epilogue ------------------------
// R17 schedule with MINIMAL barriers (3/K-tile instead of 8):
//  - ph1: vmcnt(4)+BAR  (cross-wave visibility of this tile's A1,A3)
//  - ph3: vmcnt(2)+BAR  (visibility of next tile's A0,A2,B0-B3)
//  - ph3 trailing BAR   (all waves' LDS reads retired before buffer restage)
// Lockstep barriers removed -> waves drift, LDS reads overlap MFMA across
// waves. sched_barrier(0) after each lgkmcnt(0) (rule: hipcc hoists
// register-only MFMA past inline-asm lgkmcnt despite "memory" clobber).
__launch_bounds__(512, 2)
__global__ void egemm8(const short* __restrict__ Ain, const short* __restrict__ Aout,
                       const short* __restrict__ G2T, const float* __restrict__ bm,
                       const short* __restrict__ W2T, short* __restrict__ Dt,
                       int e0, int EC) {
  __shared__ __align__(16) short SMEM[65536];    // 128 KB
  short* As0 = SMEM;            // [2][16384]
  short* Bs0 = SMEM + 32768;    // [2][16384]

  const int tid = threadIdx.x;
  const int lane = tid & 63, wid = tid >> 6;
  const int wm = wid >> 2, wn = wid & 3;
  const int fr = lane & 15, fq = lane >> 4;
  const int m0 = blockIdx.x * 256;       // e-row tile
  const int n0 = blockIdx.y * 256;       // column band = batch
  const size_t arow0 = (size_t)(e0 + m0) * 1024;

  const int rl = tid >> 3;
  const int ce = ((tid & 7) ^ (rl & 7)) << 3;
  const int ldst = wid << 9;

  f32x4 acc[8][4] = {};

  auto stageA = [&](int buf, int kt, int iss) {
    const short* s = (kt < 1024 ? Ain : Aout) + arow0
                   + (size_t)(iss * 64 + rl) * 1024 + (kt & 1023) + ce;
    glds16(&As0[buf * 16384 + iss * 4096 + ldst], s);
  };
  auto stageB = [&](int buf, int kt, int iss) {
    const short* s = G2T + (size_t)(n0 + iss * 64 + rl) * 2048 + kt + ce;
    glds16(&Bs0[buf * 16384 + iss * 4096 + ldst], s);
  };

#define EG_PHASE(QM, QN, STAGES, WAITBAR, TRAIL)                                  \
  {                                                                               \
    bf16x8 af[4][2], bv[2][2];                                                    \
    _Pragma("unroll")                                                             \
    for (int i = 0; i < 4; ++i) {                                                 \
      int r = wm * 128 + ((QM) * 4 + i) * 16 + fr;                                \
      _Pragma("unroll")                                                           \
      for (int s = 0; s < 2; ++s)                                                 \
        af[i][s] = *(const bf16x8*)&As0[buf * 16384 + r * 64 + (((s * 4 + fq) ^ (r & 7)) << 3)]; \
    }                                                                             \
    _Pragma("unroll")                                                             \
    for (int j = 0; j < 2; ++j) {                                                 \
      int rb = wn * 64 + ((QN) * 2 + j) * 16 + fr;                                \
      _Pragma("unroll")                                                           \
      for (int s = 0; s < 2; ++s)                                                 \
        bv[j][s] = *(const bf16x8*)&Bs0[buf * 16384 + rb * 64 + (((s * 4 + fq) ^ (rb & 7)) << 3)]; \
    }                                                                             \
    STAGES                                                                        \
    WAITBAR                                                                       \
    asm volatile("s_waitcnt lgkmcnt(0)" ::: "memory");                            \
    __builtin_amdgcn_sched_barrier(0);                                            \
    __builtin_amdgcn_s_setprio(1);                                                \
    _Pragma("unroll")                                                             \
    for (int i = 0; i < 4; ++i)                                                   \
      _Pragma("unroll")                                                           \
      for (int j = 0; j < 2; ++j) {                                               \
        acc[(QM) * 4 + i][(QN) * 2 + j] = __builtin_amdgcn_mfma_f32_16x16x32_bf16(\
            af[i][0], bv[j][0], acc[(QM) * 4 + i][(QN) * 2 + j], 0, 0, 0);        \
        acc[(QM) * 4 + i][(QN) * 2 + j] = __builtin_amdgcn_mfma_f32_16x16x32_bf16(\
            af[i][1], bv[j][1], acc[(QM) * 4 + i][(QN) * 2 + j], 0, 0, 0);        \
      }                                                                           \
    __builtin_amdgcn_s_setprio(0);                                                \
    TRAIL                                                                         \
  }

  #pragma unroll
  for (int i = 0; i < 4; ++i) stageA(0, 0, i);
  #pragma unroll
  for (int i = 0; i < 4; ++i) stageB(0, 0, i);
  asm volatile("s_waitcnt vmcnt(0)" ::: "memory");
  BAR();

  constexpr int NT = 2048 / 64;
  for (int t = 0; t < NT; ++t) {
    const int buf = t & 1, nb = buf ^ 1, ktn = (t + 1) * 64;
    const bool pre = (t + 1 < NT);
    EG_PHASE(0, 0, { if (pre) { stageA(nb, ktn, 0); stageA(nb, ktn, 2); } }, ;, ;)
    EG_PHASE(0, 1, { if (pre) { stageB(nb, ktn, 0); stageB(nb, ktn, 1); } },
             { asm volatile("s_waitcnt vmcnt(4)" ::: "memory"); BAR(); }, ;)
    EG_PHASE(1, 0, { if (pre) { stageB(nb, ktn, 2); stageB(nb, ktn, 3); } }, ;, ;)
    EG_PHASE(1, 1, { if (pre) { stageA(nb, ktn, 1); stageA(nb, ktn, 3); } },
             { asm volatile("s_waitcnt vmcnt(2)" ::: "memory"); BAR(); }, BAR();)
  }
#undef EG_PHASE

  // ---- fused D epilogue ----------------------------------------------
  #pragma unroll
  for (int i = 0; i < 8; ++i) {
    int eb = wm * 128 + i * 16 + fq * 4;
    #pragma unroll
    for (int j = 0; j < 4; ++j) {
      int f = wn * 64 + j * 16 + fr;
      float bb = bm[f];
      #pragma unroll
      for (int r = 0; r < 4; ++r) {
        int er = eb + r;
        SMEM[er * 256 + ((((f >> 3) ^ (er & 7)) << 3) | (f & 7))] =
            f2bf(fmaxf(acc[i][j][r] + bb, 0.0f));
      }
    }
  }
  asm volatile("s_waitcnt lgkmcnt(0)" ::: "memory");
  BAR();
  bf16x8 w2f[2][8];
  #pragma unroll
  for (int jj = 0; jj < 2; ++jj) {
    int row = wn * 32 + jj * 16 + fr;
    #pragma unroll
    for (int kk = 0; kk < 8; ++kk)
      w2f[jj][kk] = *(const bf16x8*)(W2T + (size_t)row * 256 + kk * 32 + fq * 8);
  }
  f32x4 dacc[8][2] = {};
  #pragma unroll
  for (int kk = 0; kk < 8; ++kk) {
    #pragma unroll
    for (int ii = 0; ii < 8; ++ii) {
      int er = wm * 128 + ii * 16 + fr;
      bf16x8 a = *(const bf16x8*)&SMEM[er * 256 + (((kk * 4 + fq) ^ (er & 7)) << 3)];
      dacc[ii][0] = __builtin_amdgcn_mfma_f32_16x16x32_bf16(a, w2f[0][kk], dacc[ii][0], 0, 0, 0);
      dacc[ii][1] = __builtin_amdgcn_mfma_f32_16x16x32_bf16(a, w2f[1][kk], dacc[ii][1], 0, 0, 0);
    }
  }
  const int bcol = blockIdx.y;
  #pragma unroll
  for (int ii = 0; ii < 8; ++ii) {
    int e = m0 + wm * 128 + ii * 16 + fq * 4;
    #pragma unroll
    for (int jj = 0; jj < 2; ++jj) {
      int frow = bcol * 128 + wn * 32 + jj * 16 + fr;
      short4 pk;
      pk.x = f2bf(dacc[ii][jj][0]);
      pk.y = f2bf(dacc[ii][jj][1]);
      pk.z = f2bf(dacc[ii][jj][2]);
      pk.w = f2bf(dacc[ii][jj][3]);
      *(short4*)&Dt[(size_t)frow * EC + e] = pk;
    }
  }
}

// ---- launch --------------------------------------------------------------
extern "C" void kernel_launch(void* const* d_in, const int* in_sizes, int n_in,
                              void* d_out, int out_size, void* d_ws, size_t ws_size,
                              hipStream_t stream) {
  const float* x     = (const float*)d_in[0];
  const int*   ei    = (const int*)d_in[1];
  const float* m_in  = (const float*)d_in[2];
  const float* m_out = (const float*)d_in[3];
  const float* W1    = (const float*)d_in[4];
  const float* b1    = (const float*)d_in[5];
  const float* Wm    = (const float*)d_in[6];
  const float* bm    = (const float*)d_in[7];
  const float* W2    = (const float*)d_in[8];
  const float* b2    = (const float*)d_in[9];
  float* out = (float*)d_out;
  const int* src = ei;
  const int* dst = ei + NE;

  char* w = (char*)d_ws;
  size_t used = 0;
  auto alloc = [&](size_t bytes) {
    char* p = w; size_t r = (bytes + 255) & ~(size_t)255;
    w += r; used += r; return p;
  };
  int*   deg    = (int*)  alloc((size_t)NN * 4);
  short* Adjb   = (short*)alloc((size_t)NN * NN * 2);        // 2 MB
  short* W1T    = (short*)alloc((size_t)FH * FIN * 2);
  short* WmT    = (short*)alloc((size_t)2 * FH * FH * 2);
  short* W2T    = (short*)alloc((size_t)FOUT * FH * 2);
  short* G2T    = (short*)alloc((size_t)2048 * 2048 * 2);    // 8 MB [(b,f)][(h,node)]
  float* H2X    = (float*)alloc((size_t)NN * 1024 * 4);      // 4 MB (atomic fallback)
  short* m_in_bf  = (short*)alloc((size_t)NE * NN * 2);      // 64 MB
  short* m_out_bf = (short*)alloc((size_t)NE * NN * 2);      // 64 MB
  short* m_inT    = (short*)alloc((size_t)NN * NE * 2);      // 64 MB [1024][32768]

  // union region U: {Adj,XW1T,Hb} -> {Dt} -> {XW2T}
  int EC = 4096;
  for (int ec : {32768, 16384, 8192}) {
    size_t need = (size_t)ec * 2048;   // Dt = ec*1024*2 bytes
    if (need < (12u << 20)) need = 12u << 20;
    if (used + need + (1u << 20) <= ws_size) { EC = ec; break; }
  }
  size_t ubytes = (size_t)EC * 2048;
  if (ubytes < (12u << 20)) ubytes = 12u << 20;
  char* U = alloc(ubytes);
  float* Adj  = (float*)U;                        // 4 MB   (early)
  short* XW1T = (short*)(U + (4u << 20));         // 4 MB   (early) [256][8192]
  short* Hb   = (short*)(U + (8u << 20));         // 4 MB   (early) [8192][256]
  short* Dt   = (short*)U;                        // EC*1024*2 (mid) [1024][EC]
  short* XW2T = (short*)U;                        // 2 MB   (late)  [128][8192]

  const int nchunk = NE / EC;
  const int nsplit = 8;
  bool plain = (used + (size_t)nsplit * 4 * (1u << 20) + (1u << 20) <= ws_size);
  float* Part = plain ? (float*)alloc((size_t)nsplit * 4 * (1u << 20)) : nullptr;

  hipMemsetAsync(deg, 0, (size_t)NN * 4, stream);
  hipMemsetAsync(Adj, 0, (size_t)NN * NN * 4, stream);
  if (!plain) hipMemsetAsync(H2X, 0, (size_t)NN * 1024 * 4, stream);

  k_deg<<<(NE + 255) / 256, 256, 0, stream>>>(dst, deg);
  k_adj<<<(NE + NN + 255) / 256, 256, 0, stream>>>(src, dst, deg, Adj);
  k_cast<<<NN * NN / 4 / 256, 256, 0, stream>>>((const float4*)Adj, Adjb);

  k_wt<<<(128 * 256 + 512 * 256 + 256 * 128) / 256, 256, 0, stream>>>(
      W1, Wm, W2, W1T, WmT, W2T);
  k_prep<<<dim3(NE / 64, NN / 64, 2), 256, 0, stream>>>(
      m_in, m_out, m_in_bf, m_out_bf, m_inT);

  // XW1T = (x @ W1)^T  bf16 [256][8192]
  gemm_mfma<0, 2, 0, false, false><<<dim3(2, 64, 1), 256, 0, stream>>>(
      nullptr, x, W1T, nullptr, XW1T, FIN, FIN, MR, FIN, 0, 1, 0, 0, 0, 0, 0, 1.0f);

  // Hb = relu(Adjb @ XW1_b + b1)  bf16 [8192][256]
  gemm_mfma<2, 0, 1, true, true><<<dim3(2, 8, NB), 256, 0, stream>>>(
      Adjb, nullptr, XW1T, b1, Hb,
      NN, 0, FH, NN, 0, 1, 1024, 0, 0, (size_t)NN * FH, 0, 1.0f);

  // G2T[(b,f)][(h,node)] = sum_c WmT[h][f][c] * Hb[b][node][c]
  gemm_mfma<2, 0, 0, false, false><<<dim3(8, 2, 16), 256, 0, stream>>>(
      WmT, nullptr, Hb, nullptr, G2T,
      FH, FH, 2048, FH, 0, 2, 0,
      (size_t)FH * FH, (size_t)NN * FH, (size_t)FH * 2048, 1024, 1.0f);

  for (int c = 0; c < nchunk; ++c) {
    // Dt[(b,f128)][e] = relu([m_in|m_out] @ G2T^T + bm) @ W2  (fused)
    egemm8<<<dim3(EC / 256, 8, 1), 512, 0, stream>>>(
        m_in_bf, m_out_bf, G2T, bm, W2T, Dt, c * EC, EC);
    if (plain) {
      gemm_mfma<4, 0, 0, false, false><<<dim3(8, 8, nsplit), 256, 0, stream>>>(
          m_inT + (size_t)c * EC, nullptr, Dt, nullptr, Part,
          32768, EC, 1024, EC, EC / nsplit, 1, 0, 0, 0,
          (size_t)1024 * 1024, 0, c == 0 ? 0.0f : 1.0f);
    } else {
      gemm_mfma<1, 0, 0, false, false><<<dim3(8, 8, nsplit), 256, 0, stream>>>(
          m_inT + (size_t)c * EC, nullptr, Dt, nullptr, H2X,
          32768, EC, 1024, EC, EC / nsplit, 1, 0, 0, 0, 0, 0, 1.0f);
    }
  }

  // XW2T[f128][(b,node)] = bf16(sum partials / 1024)
  if (plain) k_repack3<<<dim3(32, 32), 256, 0, stream>>>(Part, XW2T, nsplit);
  else       k_repack2<<<dim3(32, 32), 256, 0, stream>>>(H2X, XW2T);

  // out_b = Adjb @ XW2_b + b2  fp32 [8192][128]
  gemm_mfma<3, 0, 1, true, false><<<dim3(1, 8, NB), 256, 0, stream>>>(
      Adjb, nullptr, XW2T, b2, out,
      NN, 0, FOUT, NN, 0, 1, 1024, 0, 0, (size_t)NN * FOUT, 0, 1.0f);
}

// Round 19
// 555.052 us; speedup vs baseline: 1.1086x; 1.0103x over previous
//
#include <hip/hip_runtime.h>
#include <hip/hip_bf16.h>

typedef __attribute__((ext_vector_type(8))) short bf16x8;
typedef __attribute__((ext_vector_type(4))) float f32x4;

static constexpr int NB   = 8;
static constexpr int NN   = 1024;
static constexpr int NE   = 32768;
static constexpr int FIN  = 128;
static constexpr int FH   = 256;
static constexpr int FOUT = 128;
static constexpr int MR   = NB * NN;

__device__ __forceinline__ short f2bf(float f) {
  union { __hip_bfloat16 h; short s; } u;
  u.h = __float2bfloat16(f);
  return u.s;
}

typedef const __attribute__((address_space(1))) void gas_void;
typedef __attribute__((address_space(3))) void las_void;
__device__ __forceinline__ void glds16(short* lds, const short* g) {
  __builtin_amdgcn_global_load_lds((gas_void*)g, (las_void*)lds, 16, 0, 0);
}
__device__ __forceinline__ void BAR() {
  asm volatile("" ::: "memory");
  __builtin_amdgcn_s_barrier();
  asm volatile("" ::: "memory");
}

// ---- graph preprocessing -------------------------------------------------
__global__ void k_deg(const int* __restrict__ dst, int* __restrict__ deg) {
  int e = blockIdx.x * blockDim.x + threadIdx.x;
  if (e < NE) atomicAdd(&deg[dst[e]], 1);
}
__global__ void k_adj(const int* __restrict__ src, const int* __restrict__ dst,
                      const int* __restrict__ deg, float* __restrict__ Adj) {
  int t = blockIdx.x * blockDim.x + threadIdx.x;
  if (t < NE) {
    int s = src[t], d = dst[t];
    float ds = rsqrtf((float)(deg[s] + 1));
    float dd = rsqrtf((float)(deg[d] + 1));
    atomicAdd(&Adj[d * NN + s], ds * dd);
  } else if (t < NE + NN) {
    int n = t - NE;
    float dn = rsqrtf((float)(deg[n] + 1));
    atomicAdd(&Adj[n * NN + n], dn * dn);
  }
}

// ---- layout / cast kernels ----------------------------------------------
__global__ __launch_bounds__(256) void k_cast(const float4* __restrict__ S,
                                              short* __restrict__ D) {
  size_t q = (size_t)blockIdx.x * 256 + threadIdx.x;
  float4 a = S[q];
  short4 p;
  p.x = f2bf(a.x); p.y = f2bf(a.y); p.z = f2bf(a.z); p.w = f2bf(a.w);
  *(short4*)&D[q * 4] = p;
}
__global__ __launch_bounds__(256) void k_wt(const float* __restrict__ W1,
                                            const float* __restrict__ Wm,
                                            const float* __restrict__ W2,
                                            short* __restrict__ W1T,
                                            short* __restrict__ WmT,
                                            short* __restrict__ W2T) {
  int idx = blockIdx.x * 256 + threadIdx.x;
  if (idx < 128 * 256) {
    int r = idx >> 8, c = idx & 255;
    W1T[c * 128 + r] = f2bf(W1[idx]);
  } else if (idx < 128 * 256 + 512 * 256) {
    int k = idx - 128 * 256;
    int r = k >> 8, c = k & 255;
    int h = r >> 8, kk = r & 255;
    WmT[h * 65536 + c * 256 + kk] = f2bf(Wm[k]);
  } else {
    int k = idx - 128 * 256 - 512 * 256;
    int r = k >> 7, c = k & 127;
    W2T[c * 256 + r] = f2bf(W2[k]);
  }
}
// z=0: m_in -> mi_bf (vectorized) + miT (tile transpose); z=1: m_out -> mo_bf
__global__ __launch_bounds__(256) void k_prep(const float* __restrict__ mi,
                                              const float* __restrict__ mo,
                                              short* __restrict__ mi_bf,
                                              short* __restrict__ mo_bf,
                                              short* __restrict__ miT) {
  int tid = threadIdx.x;
  int e0 = blockIdx.x * 64, n0 = blockIdx.y * 64;
  if (blockIdx.z == 1) {
    #pragma unroll
    for (int it = 0; it < 4; ++it) {
      int r = it * 16 + (tid >> 4);
      int c4 = (tid & 15) * 4;
      float4 v = *(const float4*)&mo[(size_t)(e0 + r) * 1024 + n0 + c4];
      short4 p;
      p.x = f2bf(v.x); p.y = f2bf(v.y); p.z = f2bf(v.z); p.w = f2bf(v.w);
      *(short4*)&mo_bf[(size_t)(e0 + r) * 1024 + n0 + c4] = p;
    }
    return;
  }
  __shared__ short tile[64][71];
  #pragma unroll
  for (int it = 0; it < 4; ++it) {
    int r = it * 16 + (tid >> 4);
    int c4 = (tid & 15) * 4;
    float4 v = *(const float4*)&mi[(size_t)(e0 + r) * 1024 + n0 + c4];
    short4 p;
    p.x = f2bf(v.x); p.y = f2bf(v.y); p.z = f2bf(v.z); p.w = f2bf(v.w);
    *(short4*)&mi_bf[(size_t)(e0 + r) * 1024 + n0 + c4] = p;
    tile[c4 + 0][r] = p.x;
    tile[c4 + 1][r] = p.y;
    tile[c4 + 2][r] = p.z;
    tile[c4 + 3][r] = p.w;
  }
  __syncthreads();
  int n = tid >> 2, ec = (tid & 3) * 16;
  #pragma unroll
  for (int q = 0; q < 4; ++q) {
    short4 v;
    v.x = tile[n][ec + q * 4 + 0];
    v.y = tile[n][ec + q * 4 + 1];
    v.z = tile[n][ec + q * 4 + 2];
    v.w = tile[n][ec + q * 4 + 3];
    *(short4*)&miT[(size_t)(n0 + n) * 32768 + e0 + ec + q * 4] = v;
  }
}
// atomic-path repack: XW2T[f128][(b,node)] = bf16(H2X[node][b*128+f] / 1024)
__global__ __launch_bounds__(256) void k_repack2(const float* __restrict__ H2X,
                                                 short* __restrict__ XW2T) {
  __shared__ float t[32][33];
  int n0 = blockIdx.x * 32, c0 = blockIdx.y * 32;
  int r = threadIdx.x >> 5, cc = threadIdx.x & 31;
  #pragma unroll
  for (int p = 0; p < 4; ++p)
    t[r + p * 8][cc] = H2X[(size_t)(n0 + r + p * 8) * 1024 + c0 + cc];
  __syncthreads();
  const float inv = 1.0f / 1024.0f;
  #pragma unroll
  for (int p = 0; p < 4; ++p) {
    int c = c0 + r + p * 8;
    int b = c >> 7, f = c & 127;
    XW2T[(size_t)f * 8192 + b * 1024 + n0 + cc] = f2bf(t[cc][r + p * 8] * inv);
  }
}
// plain-path: sum ns partials, /1024, transpose-store
__global__ __launch_bounds__(256) void k_repack3(const float* __restrict__ Part,
                                                 short* __restrict__ XW2T, int ns) {
  __shared__ float t[32][33];
  int n0 = blockIdx.x * 32, c0 = blockIdx.y * 32;
  int r = threadIdx.x >> 5, cc = threadIdx.x & 31;
  #pragma unroll
  for (int p = 0; p < 4; ++p) {
    size_t base = (size_t)(n0 + r + p * 8) * 1024 + c0 + cc;
    float s = 0.0f;
    for (int z = 0; z < ns; ++z) s += Part[(size_t)z * 1024 * 1024 + base];
    t[r + p * 8][cc] = s;
  }
  __syncthreads();
  const float inv = 1.0f / 1024.0f;
  #pragma unroll
  for (int p = 0; p < 4; ++p) {
    int c = c0 + r + p * 8;
    int b = c >> 7, f = c & 127;
    XW2T[(size_t)f * 8192 + b * 1024 + n0 + cc] = f2bf(t[cc][r + p * 8] * inv);
  }
}

// ---- proven 128x128 bf16 MFMA GEMM: C = A[M,K] @ BT[N,K]^T ---------------
template <int EPI, int ASRC, int BSEL, bool BIAS, bool RELU>
__launch_bounds__(256)
__global__ void gemm_mfma(const short* __restrict__ Ab, const float* __restrict__ Af,
                          const short* __restrict__ BT, const float* __restrict__ bias,
                          void* __restrict__ Cv,
                          int lda, int ldb, int ldc, int K, int kSplit, int nz2,
                          int zcolB, size_t szA, size_t szB, size_t szC, size_t szC2,
                          float scale) {
  __shared__ __align__(16) short As[128 * 64];
  __shared__ __align__(16) short Bs[128 * 64];

  const int tid = threadIdx.x;
  const int lane = tid & 63, wid = tid >> 6;
  const int wr = wid >> 1, wc = wid & 1;
  const int fr = lane & 15, fq = lane >> 4;
  const int m0 = blockIdx.y * 128, n0 = blockIdx.x * 128;

  int zA = 0, zB = 0, k0 = 0, k1 = K;
  if constexpr (EPI == 1 || EPI == 4) {
    k0 = blockIdx.z * kSplit; k1 = k0 + kSplit;
  } else {
    zA = (int)blockIdx.z % nz2; zB = (int)blockIdx.z / nz2;
  }
  if constexpr (ASRC == 0) Ab += (size_t)zA * szA;
  else                     Af += (size_t)zA * szA;
  BT += (size_t)zB * szB;
  const int colB = zB * zcolB;

  const int rq = lane >> 3;
  const int ks = (lane & 7) ^ rq;

  f32x4 acc[4][4] = {};

  for (int kt = k0; kt < k1; kt += 64) {
    if constexpr (ASRC == 2) {
      #pragma unroll
      for (int p = 0; p < 4; ++p) {
        int i = p * 256 + tid, row = i >> 3, g = i & 7;
        const float* ap = Af + (size_t)(m0 + row) * lda + kt + g * 8;
        bf16x8 v;
        #pragma unroll
        for (int e = 0; e < 8; ++e) v[e] = f2bf(ap[e]);
        *(bf16x8*)&As[row * 64 + ((g ^ (row & 7)) * 8)] = v;
      }
    } else {
      #pragma unroll
      for (int c = 0; c < 4; ++c) {
        int row = wid * 32 + c * 8 + rq;
        glds16(&As[(wid * 256 + c * 64) * 8],
               Ab + (size_t)(m0 + row) * lda + kt + ks * 8);
      }
    }
    {
      const short* Bsrc;
      int ldbe;
      if constexpr (BSEL == 1) { Bsrc = BT + colB; ldbe = 8192; }
      else                     { Bsrc = BT;        ldbe = ldb;  }
      #pragma unroll
      for (int c = 0; c < 4; ++c) {
        int row = wid * 32 + c * 8 + rq;
        glds16(&Bs[(wid * 256 + c * 64) * 8],
               Bsrc + (size_t)(n0 + row) * ldbe + kt + ks * 8);
      }
    }
    __syncthreads();
    bf16x8 afv[4][2], bfv[4][2];
    #pragma unroll
    for (int i = 0; i < 4; ++i) {
      int row = wr * 64 + i * 16 + fr;
      #pragma unroll
      for (int kh = 0; kh < 2; ++kh)
        afv[i][kh] = *(const bf16x8*)&As[row * 64 + (((kh * 4 + fq) ^ (fr & 7)) * 8)];
    }
    #pragma unroll
    for (int j = 0; j < 4; ++j) {
      int row = wc * 64 + j * 16 + fr;
      #pragma unroll
      for (int kh = 0; kh < 2; ++kh)
        bfv[j][kh] = *(const bf16x8*)&Bs[row * 64 + (((kh * 4 + fq) ^ (fr & 7)) * 8)];
    }
    #pragma unroll
    for (int i = 0; i < 4; ++i)
      #pragma unroll
      for (int j = 0; j < 4; ++j) {
        acc[i][j] = __builtin_amdgcn_mfma_f32_16x16x32_bf16(afv[i][0], bfv[j][0], acc[i][j], 0, 0, 0);
        acc[i][j] = __builtin_amdgcn_mfma_f32_16x16x32_bf16(afv[i][1], bfv[j][1], acc[i][j], 0, 0, 0);
      }
    __syncthreads();
  }

  const size_t cOff = (size_t)zB * szC + (size_t)zA * szC2;
  #pragma unroll
  for (int i = 0; i < 4; ++i) {
    int rowb = m0 + wr * 64 + i * 16 + fq * 4;
    #pragma unroll
    for (int j = 0; j < 4; ++j) {
      int col = n0 + wc * 64 + j * 16 + fr;
      float bv = 0.0f;
      if constexpr (BIAS) bv = bias[col];
      float v0 = acc[i][j][0] + bv, v1 = acc[i][j][1] + bv;
      float v2 = acc[i][j][2] + bv, v3 = acc[i][j][3] + bv;
      if constexpr (RELU) {
        v0 = fmaxf(v0, 0.0f); v1 = fmaxf(v1, 0.0f);
        v2 = fmaxf(v2, 0.0f); v3 = fmaxf(v3, 0.0f);
      }
      if constexpr (EPI == 0) {
        short* Ct = (short*)Cv + cOff;
        short4 pk;
        pk.x = f2bf(v0); pk.y = f2bf(v1); pk.z = f2bf(v2); pk.w = f2bf(v3);
        *(short4*)(Ct + (size_t)col * ldc + rowb) = pk;
      } else if constexpr (EPI == 1) {
        float* Cf = (float*)Cv;
        atomicAdd(&Cf[(size_t)(rowb + 0) * ldc + col], acc[i][j][0] * scale);
        atomicAdd(&Cf[(size_t)(rowb + 1) * ldc + col], acc[i][j][1] * scale);
        atomicAdd(&Cf[(size_t)(rowb + 2) * ldc + col], acc[i][j][2] * scale);
        atomicAdd(&Cf[(size_t)(rowb + 3) * ldc + col], acc[i][j][3] * scale);
      } else if constexpr (EPI == 2) {
        short* Cn = (short*)Cv + cOff;
        Cn[(size_t)(rowb + 0) * ldc + col] = f2bf(v0);
        Cn[(size_t)(rowb + 1) * ldc + col] = f2bf(v1);
        Cn[(size_t)(rowb + 2) * ldc + col] = f2bf(v2);
        Cn[(size_t)(rowb + 3) * ldc + col] = f2bf(v3);
      } else if constexpr (EPI == 4) {
        float* Cf = (float*)Cv + (size_t)blockIdx.z * szC;
        #pragma unroll
        for (int r = 0; r < 4; ++r) {
          float* p = &Cf[(size_t)(rowb + r) * ldc + col];
          float old = (scale != 0.0f) ? *p : 0.0f;
          *p = old + acc[i][j][r];
        }
      } else {
        float* Cf = (float*)Cv + cOff;
        Cf[(size_t)(rowb + 0) * ldc + col] = v0;
        Cf[(size_t)(rowb + 1) * ldc + col] = v1;
        Cf[(size_t)(rowb + 2) * ldc + col] = v2;
        Cf[(size_t)(rowb + 3) * ldc + col] = v3;
      }
    }
  }
}

// ---- 256x256 edge GEMM, barrier-light (R18) + serpentine register reuse --
// Phase order (0,0)->(0,1)->(1,1)->(1,0): A-half held across 2 phases, both
// B-pairs held across the tile -> 24 LDS b128/wave/K-tile (was 48). Same
// vmcnt/BAR discipline as R18 (audited; per-wave outstanding 6->4 / 8->2).
__launch_bounds__(512, 2)
__global__ void egemm8(const short* __restrict__ Ain, const short* __restrict__ Aout,
                       const short* __restrict__ G2T, const float* __restrict__ bm,
                       const short* __restrict__ W2T, short* __restrict__ Dt,
                       int e0, int EC) {
  __shared__ __align__(16) short SMEM[65536];    // 128 KB
  short* As0 = SMEM;            // [2][16384]
  short* Bs0 = SMEM + 32768;    // [2][16384]

  const int tid = threadIdx.x;
  const int lane = tid & 63, wid = tid >> 6;
  const int wm = wid >> 2, wn = wid & 3;
  const int fr = lane & 15, fq = lane >> 4;
  const int m0 = blockIdx.x * 256;       // e-row tile
  const int n0 = blockIdx.y * 256;       // column band = batch
  const size_t arow0 = (size_t)(e0 + m0) * 1024;

  const int rl = tid >> 3;
  const int ce = ((tid & 7) ^ (rl & 7)) << 3;
  const int ldst = wid << 9;

  f32x4 acc[8][4] = {};

  auto stageA = [&](int buf, int kt, int iss) {
    const short* s = (kt < 1024 ? Ain : Aout) + arow0
                   + (size_t)(iss * 64 + rl) * 1024 + (kt & 1023) + ce;
    glds16(&As0[buf * 16384 + iss * 4096 + ldst], s);
  };
  auto stageB = [&](int buf, int kt, int iss) {
    const short* s = G2T + (size_t)(n0 + iss * 64 + rl) * 2048 + kt + ce;
    glds16(&Bs0[buf * 16384 + iss * 4096 + ldst], s);
  };

#define MFMA16(QM, QN, BV)                                                        \
  __builtin_amdgcn_s_setprio(1);                                                  \
  _Pragma("unroll")                                                               \
  for (int i = 0; i < 4; ++i)                                                     \
    _Pragma("unroll")                                                             \
    for (int j = 0; j < 2; ++j) {                                                 \
      acc[(QM) * 4 + i][(QN) * 2 + j] = __builtin_amdgcn_mfma_f32_16x16x32_bf16(  \
          af[i][0], BV[j][0], acc[(QM) * 4 + i][(QN) * 2 + j], 0, 0, 0);          \
      acc[(QM) * 4 + i][(QN) * 2 + j] = __builtin_amdgcn_mfma_f32_16x16x32_bf16(  \
          af[i][1], BV[j][1], acc[(QM) * 4 + i][(QN) * 2 + j], 0, 0, 0);          \
    }                                                                             \
  __builtin_amdgcn_s_setprio(0);

  #pragma unroll
  for (int i = 0; i < 4; ++i) stageA(0, 0, i);
  #pragma unroll
  for (int i = 0; i < 4; ++i) stageB(0, 0, i);
  asm volatile("s_waitcnt vmcnt(0)" ::: "memory");
  BAR();

  constexpr int NT = 2048 / 64;
  for (int t = 0; t < NT; ++t) {
    const int buf = t & 1, nb = buf ^ 1, ktn = (t + 1) * 64;
    const bool pre = (t + 1 < NT);
    bf16x8 af[4][2], bv0[2][2], bv1[2][2];
    // ---- phase (0,0): read A-half0 + B0; stage A0,A2(t+1)
    #pragma unroll
    for (int i = 0; i < 4; ++i) {
      int r = wm * 128 + i * 16 + fr;
      #pragma unroll
      for (int s = 0; s < 2; ++s)
        af[i][s] = *(const bf16x8*)&As0[buf * 16384 + r * 64 + (((s * 4 + fq) ^ (r & 7)) << 3)];
    }
    #pragma unroll
    for (int j = 0; j < 2; ++j) {
      int rb = wn * 64 + j * 16 + fr;
      #pragma unroll
      for (int s = 0; s < 2; ++s)
        bv0[j][s] = *(const bf16x8*)&Bs0[buf * 16384 + rb * 64 + (((s * 4 + fq) ^ (rb & 7)) << 3)];
    }
    if (pre) { stageA(nb, ktn, 0); stageA(nb, ktn, 2); }
    asm volatile("s_waitcnt lgkmcnt(0)" ::: "memory");
    __builtin_amdgcn_sched_barrier(0);
    MFMA16(0, 0, bv0)
    // ---- phase (0,1): read B1; stage B0,B1(t+1); vmcnt(4)+BAR (A1,A3 of t)
    #pragma unroll
    for (int j = 0; j < 2; ++j) {
      int rb = wn * 64 + (2 + j) * 16 + fr;
      #pragma unroll
      for (int s = 0; s < 2; ++s)
        bv1[j][s] = *(const bf16x8*)&Bs0[buf * 16384 + rb * 64 + (((s * 4 + fq) ^ (rb & 7)) << 3)];
    }
    if (pre) { stageB(nb, ktn, 0); stageB(nb, ktn, 1); }
    asm volatile("s_waitcnt vmcnt(4)" ::: "memory");
    BAR();
    asm volatile("s_waitcnt lgkmcnt(0)" ::: "memory");
    __builtin_amdgcn_sched_barrier(0);
    MFMA16(0, 1, bv1)
    // ---- phase (1,1): read A-half1 (hold B1); stage B2,B3(t+1)
    #pragma unroll
    for (int i = 0; i < 4; ++i) {
      int r = wm * 128 + (4 + i) * 16 + fr;
      #pragma unroll
      for (int s = 0; s < 2; ++s)
        af[i][s] = *(const bf16x8*)&As0[buf * 16384 + r * 64 + (((s * 4 + fq) ^ (r & 7)) << 3)];
    }
    if (pre) { stageB(nb, ktn, 2); stageB(nb, ktn, 3); }
    asm volatile("s_waitcnt lgkmcnt(0)" ::: "memory");
    __builtin_amdgcn_sched_barrier(0);
    MFMA16(1, 1, bv1)
    // ---- phase (1,0): no LDS reads (hold A1, B0); stage A1,A3(t+1);
    //      vmcnt(2)+BAR (next tile's A0,A2,B0-B3); trailing BAR (restage guard)
    if (pre) { stageA(nb, ktn, 1); stageA(nb, ktn, 3); }
    asm volatile("s_waitcnt vmcnt(2)" ::: "memory");
    BAR();
    MFMA16(1, 0, bv0)
    BAR();
  }
#undef MFMA16

  // ---- fused D epilogue ----------------------------------------------
  #pragma unroll
  for (int i = 0; i < 8; ++i) {
    int eb = wm * 128 + i * 16 + fq * 4;
    #pragma unroll
    for (int j = 0; j < 4; ++j) {
      int f = wn * 64 + j * 16 + fr;
      float bb = bm[f];
      #pragma unroll
      for (int r = 0; r < 4; ++r) {
        int er = eb + r;
        SMEM[er * 256 + ((((f >> 3) ^ (er & 7)) << 3) | (f & 7))] =
            f2bf(fmaxf(acc[i][j][r] + bb, 0.0f));
      }
    }
  }
  asm volatile("s_waitcnt lgkmcnt(0)" ::: "memory");
  BAR();
  bf16x8 w2f[2][8];
  #pragma unroll
  for (int jj = 0; jj < 2; ++jj) {
    int row = wn * 32 + jj * 16 + fr;
    #pragma unroll
    for (int kk = 0; kk < 8; ++kk)
      w2f[jj][kk] = *(const bf16x8*)(W2T + (size_t)row * 256 + kk * 32 + fq * 8);
  }
  f32x4 dacc[8][2] = {};
  #pragma unroll
  for (int kk = 0; kk < 8; ++kk) {
    #pragma unroll
    for (int ii = 0; ii < 8; ++ii) {
      int er = wm * 128 + ii * 16 + fr;
      bf16x8 a = *(const bf16x8*)&SMEM[er * 256 + (((kk * 4 + fq) ^ (er & 7)) << 3)];
      dacc[ii][0] = __builtin_amdgcn_mfma_f32_16x16x32_bf16(a, w2f[0][kk], dacc[ii][0], 0, 0, 0);
      dacc[ii][1] = __builtin_amdgcn_mfma_f32_16x16x32_bf16(a, w2f[1][kk], dacc[ii][1], 0, 0, 0);
    }
  }
  const int bcol = blockIdx.y;
  #pragma unroll
  for (int ii = 0; ii < 8; ++ii) {
    int e = m0 + wm * 128 + ii * 16 + fq * 4;
    #pragma unroll
    for (int jj = 0; jj < 2; ++jj) {
      int frow = bcol * 128 + wn * 32 + jj * 16 + fr;
      short4 pk;
      pk.x = f2bf(dacc[ii][jj][0]);
      pk.y = f2bf(dacc[ii][jj][1]);
      pk.z = f2bf(dacc[ii][jj][2]);
      pk.w = f2bf(dacc[ii][jj][3]);
      *(short4*)&Dt[(size_t)frow * EC + e] = pk;
    }
  }
}

// ---- launch --------------------------------------------------------------
extern "C" void kernel_launch(void* const* d_in, const int* in_sizes, int n_in,
                              void* d_out, int out_size, void* d_ws, size_t ws_size,
                              hipStream_t stream) {
  const float* x     = (const float*)d_in[0];
  const int*   ei    = (const int*)d_in[1];
  const float* m_in  = (const float*)d_in[2];
  const float* m_out = (const float*)d_in[3];
  const float* W1    = (const float*)d_in[4];
  const float* b1    = (const float*)d_in[5];
  const float* Wm    = (const float*)d_in[6];
  const float* bm    = (const float*)d_in[7];
  const float* W2    = (const float*)d_in[8];
  const float* b2    = (const float*)d_in[9];
  float* out = (float*)d_out;
  const int* src = ei;
  const int* dst = ei + NE;

  char* w = (char*)d_ws;
  size_t used = 0;
  auto alloc = [&](size_t bytes) {
    char* p = w; size_t r = (bytes + 255) & ~(size_t)255;
    w += r; used += r; return p;
  };
  int*   deg    = (int*)  alloc((size_t)NN * 4);
  short* Adjb   = (short*)alloc((size_t)NN * NN * 2);        // 2 MB
  short* W1T    = (short*)alloc((size_t)FH * FIN * 2);
  short* WmT    = (short*)alloc((size_t)2 * FH * FH * 2);
  short* W2T    = (short*)alloc((size_t)FOUT * FH * 2);
  short* G2T    = (short*)alloc((size_t)2048 * 2048 * 2);    // 8 MB [(b,f)][(h,node)]
  float* H2X    = (float*)alloc((size_t)NN * 1024 * 4);      // 4 MB (atomic fallback)
  short* m_in_bf  = (short*)alloc((size_t)NE * NN * 2);      // 64 MB
  short* m_out_bf = (short*)alloc((size_t)NE * NN * 2);      // 64 MB
  short* m_inT    = (short*)alloc((size_t)NN * NE * 2);      // 64 MB [1024][32768]

  // union region U: {Adj,XW1T,Hb} -> {Dt} -> {XW2T}
  int EC = 4096;
  for (int ec : {32768, 16384, 8192}) {
    size_t need = (size_t)ec * 2048;   // Dt = ec*1024*2 bytes
    if (need < (12u << 20)) need = 12u << 20;
    if (used + need + (1u << 20) <= ws_size) { EC = ec; break; }
  }
  size_t ubytes = (size_t)EC * 2048;
  if (ubytes < (12u << 20)) ubytes = 12u << 20;
  char* U = alloc(ubytes);
  float* Adj  = (float*)U;                        // 4 MB   (early)
  short* XW1T = (short*)(U + (4u << 20));         // 4 MB   (early) [256][8192]
  short* Hb   = (short*)(U + (8u << 20));         // 4 MB   (early) [8192][256]
  short* Dt   = (short*)U;                        // EC*1024*2 (mid) [1024][EC]
  short* XW2T = (short*)U;                        // 2 MB   (late)  [128][8192]

  const int nchunk = NE / EC;
  const int nsplit = 8;
  bool plain = (used + (size_t)nsplit * 4 * (1u << 20) + (1u << 20) <= ws_size);
  float* Part = plain ? (float*)alloc((size_t)nsplit * 4 * (1u << 20)) : nullptr;

  hipMemsetAsync(deg, 0, (size_t)NN * 4, stream);
  hipMemsetAsync(Adj, 0, (size_t)NN * NN * 4, stream);
  if (!plain) hipMemsetAsync(H2X, 0, (size_t)NN * 1024 * 4, stream);

  k_deg<<<(NE + 255) / 256, 256, 0, stream>>>(dst, deg);
  k_adj<<<(NE + NN + 255) / 256, 256, 0, stream>>>(src, dst, deg, Adj);
  k_cast<<<NN * NN / 4 / 256, 256, 0, stream>>>((const float4*)Adj, Adjb);

  k_wt<<<(128 * 256 + 512 * 256 + 256 * 128) / 256, 256, 0, stream>>>(
      W1, Wm, W2, W1T, WmT, W2T);
  k_prep<<<dim3(NE / 64, NN / 64, 2), 256, 0, stream>>>(
      m_in, m_out, m_in_bf, m_out_bf, m_inT);

  // XW1T = (x @ W1)^T  bf16 [256][8192]
  gemm_mfma<0, 2, 0, false, false><<<dim3(2, 64, 1), 256, 0, stream>>>(
      nullptr, x, W1T, nullptr, XW1T, FIN, FIN, MR, FIN, 0, 1, 0, 0, 0, 0, 0, 1.0f);

  // Hb = relu(Adjb @ XW1_b + b1)  bf16 [8192][256]
  gemm_mfma<2, 0, 1, true, true><<<dim3(2, 8, NB), 256, 0, stream>>>(
      Adjb, nullptr, XW1T, b1, Hb,
      NN, 0, FH, NN, 0, 1, 1024, 0, 0, (size_t)NN * FH, 0, 1.0f);

  // G2T[(b,f)][(h,node)] = sum_c WmT[h][f][c] * Hb[b][node][c]
  gemm_mfma<2, 0, 0, false, false><<<dim3(8, 2, 16), 256, 0, stream>>>(
      WmT, nullptr, Hb, nullptr, G2T,
      FH, FH, 2048, FH, 0, 2, 0,
      (size_t)FH * FH, (size_t)NN * FH, (size_t)FH * 2048, 1024, 1.0f);

  for (int c = 0; c < nchunk; ++c) {
    // Dt[(b,f128)][e] = relu([m_in|m_out] @ G2T^T + bm) @ W2  (fused)
    egemm8<<<dim3(EC / 256, 8, 1), 512, 0, stream>>>(
        m_in_bf, m_out_bf, G2T, bm, W2T, Dt, c * EC, EC);
    if (plain) {
      gemm_mfma<4, 0, 0, false, false><<<dim3(8, 8, nsplit), 256, 0, stream>>>(
          m_inT + (size_t)c * EC, nullptr, Dt, nullptr, Part,
          32768, EC, 1024, EC, EC / nsplit, 1, 0, 0, 0,
          (size_t)1024 * 1024, 0, c == 0 ? 0.0f : 1.0f);
    } else {
      gemm_mfma<1, 0, 0, false, false><<<dim3(8, 8, nsplit), 256, 0, stream>>>(
          m_inT + (size_t)c * EC, nullptr, Dt, nullptr, H2X,
          32768, EC, 1024, EC, EC / nsplit, 1, 0, 0, 0, 0, 0, 1.0f);
    }
  }

  // XW2T[f128][(b,node)] = bf16(sum partials / 1024)
  if (plain) k_repack3<<<dim3(32, 32), 256, 0, stream>>>(Part, XW2T, nsplit);
  else       k_repack2<<<dim3(32, 32), 256, 0, stream>>>(H2X, XW2T);

  // out_b = Adjb @ XW2_b + b2  fp32 [8192][128]
  gemm_mfma<3, 0, 1, true, false><<<dim3(1, 8, NB), 256, 0, stream>>>(
      Adjb, nullptr, XW2T, b2, out,
      NN, 0, FOUT, NN, 0, 1, 1024, 0, 0, (size_t)NN * FOUT, 0, 1.0f);
}